// Round 6
// baseline (295.339 us; speedup 1.0000x reference)
//
#include <hip/hip_runtime.h>

#define NN 50000
#define EE 300000
#define ET (EE + NN)   // edges + self loops = 350000
#define CD 256
#define PAD_M 50176    // 392 * 128, covers gemm tile over-read
#define BCAP 64        // per-node src bucket capacity (max deg ~25, P(>63)<1e-30)

typedef unsigned short ushortT;
typedef short bf16x8 __attribute__((ext_vector_type(8)));
typedef float f32x4 __attribute__((ext_vector_type(4)));

__device__ __forceinline__ ushortT f2b(float f) {
    unsigned u = __builtin_bit_cast(unsigned, f);
    unsigned r = (u + 0x7FFFu + ((u >> 16) & 1u)) >> 16;
    return (ushortT)r;
}
__device__ __forceinline__ float b2f(ushortT b) {
    return __builtin_bit_cast(float, ((unsigned)b) << 16);
}

// ---------------- alpha-vector precompute: wXs = W @ a_src (row dots) ------
// (x@W)·a == x·(W@a): lets alpha1 be computed in prep (x in registers) and
// alpha2 in agg1's epilogue (fp32 acc in registers).
// grid 128: blocks [0,64) -> W1 rows, [64,128) -> W2 rows; wave per row.
// Also zeroes the bucket counters cnt[0..NN) (prep's fill section, next
// kernel on the stream, consumes them).

__global__ __launch_bounds__(256) void wvec_kernel(
    const float* __restrict__ W1, const float* __restrict__ a1s,
    const float* __restrict__ a1d, const float* __restrict__ W2,
    const float* __restrict__ a2s, const float* __restrict__ a2d,
    float* __restrict__ w1s, float* __restrict__ w1d,
    float* __restrict__ w2s, float* __restrict__ w2d,
    int* __restrict__ cnt) {
    int b = blockIdx.x;
    // bucket-counter zeroing: 128*256 = 32768 threads cover 50000 ints in 2 steps
    int g = b * 256 + threadIdx.x;
    if (g < NN) cnt[g] = 0;
    if (g + 32768 < NN) cnt[g + 32768] = 0;

    const float* W = (b < 64) ? W1 : W2;
    const float* vs = (b < 64) ? a1s : a2s;
    const float* vd = (b < 64) ? a1d : a2d;
    float* os = (b < 64) ? w1s : w2s;
    float* od = (b < 64) ? w1d : w2d;
    int r = (b & 63) * 4 + (threadIdx.x >> 6);
    int lane = threadIdx.x & 63;
    float4 wv = *(const float4*)(W + (size_t)r * CD + lane * 4);
    float4 s4 = *(const float4*)(vs + lane * 4);
    float4 d4 = *(const float4*)(vd + lane * 4);
    float ss = wv.x * s4.x + wv.y * s4.y + wv.z * s4.z + wv.w * s4.w;
    float dd = wv.x * d4.x + wv.y * d4.y + wv.z * d4.z + wv.w * d4.w;
#pragma unroll
    for (int off = 1; off < 64; off <<= 1) {
        ss += __shfl_xor(ss, off);
        dd += __shfl_xor(dd, off);
    }
    if (lane == 0) {
        os[r] = ss;
        od[r] = dd;
    }
}

// ---------------- fused preprocessing ----------------
// W matrices are emitted in MFMA-FRAGMENT order so the GEMM can load B
// operands straight from L2 into registers (no LDS stage, no barrier):
//   Bf[chunk][n][e], chunk = k>>3 (32 chunks), n = output col (256), e = k&7
//   i.e. flat index chunk*2048 + n*8 + e   (128 KB per W, same as before)
// W1/W2 need B[n][k] = W[k][n] (transpose, via 32x32 LDS tile);
// Wl needs B[n][k] = Wl[n][k] (pure reshuffle).
// Block ranges:
// [0,12500)      x rows: cast->bf16 AND alpha1 = x·w1s / x·w1d (wave per row)
// [12500,12564)  W1 -> fragment order
// [12564,12628)  W2 -> fragment order
// [12628,12660)  Wl -> fragment order
// [12660,14028)  bucket scatter (replaces fill_bucket kernel; cnt zeroed by wvec)
#define PREP_X 12500
#define PREP_W1 12564
#define PREP_W2 12628
#define PREP_WL 12660
#define PREP_END 14028

__global__ __launch_bounds__(256) void prep_kernel(
    const float* __restrict__ x, const float* __restrict__ W1,
    const float* __restrict__ W2, const float* __restrict__ Wl,
    ushortT* __restrict__ B0, ushortT* __restrict__ W1t,
    ushortT* __restrict__ W2t, ushortT* __restrict__ Wlt,
    const float* __restrict__ w1s, const float* __restrict__ w1d,
    float* __restrict__ as1, float* __restrict__ ad1,
    const int* __restrict__ ei, int* __restrict__ cnt,
    int* __restrict__ srcs) {
    __shared__ float t[32][33];
    int b = blockIdx.x, tidx = threadIdx.x;
    if (b < PREP_X) {
        int node = b * 4 + (tidx >> 6);
        int lane = tidx & 63;
        float4 v = *(const float4*)(x + (size_t)node * CD + lane * 4);
        ushort4 o;
        o.x = f2b(v.x); o.y = f2b(v.y); o.z = f2b(v.z); o.w = f2b(v.w);
        *(ushort4*)(B0 + (size_t)node * CD + lane * 4) = o;
        float4 s4 = *(const float4*)(w1s + lane * 4);
        float4 d4 = *(const float4*)(w1d + lane * 4);
        float ss = v.x * s4.x + v.y * s4.y + v.z * s4.z + v.w * s4.w;
        float dd = v.x * d4.x + v.y * d4.y + v.z * d4.z + v.w * d4.w;
#pragma unroll
        for (int off = 1; off < 64; off <<= 1) {
            ss += __shfl_xor(ss, off);
            dd += __shfl_xor(dd, off);
        }
        if (lane == 0) {
            as1[node] = ss;
            ad1[node] = dd;
        }
    } else if (b < PREP_W2) {
        // W1/W2 transpose into fragment order. Tile: k in [bx,bx+32), n in [by,by+32).
        const float* W = (b < PREP_W1) ? W1 : W2;
        ushortT* Bt = (b < PREP_W1) ? W1t : W2t;
        int rel = b - ((b < PREP_W1) ? PREP_X : PREP_W1);
        int bx = (rel & 7) * 32;   // k base
        int by = (rel >> 3) * 32;  // n base
        int xx = tidx & 31, yy = tidx >> 5;
        for (int y = yy; y < 32; y += 8) t[y][xx] = W[(size_t)(bx + y) * CD + by + xx];
        __syncthreads();
        if (tidx < 128) {
            int nl = tidx & 31;       // local n
            int kg = tidx >> 5;       // k-group (8 k's each)
            int chunk = (bx >> 3) + kg;
            ushortT o[8];
#pragma unroll
            for (int e = 0; e < 8; ++e) o[e] = f2b(t[kg * 8 + e][nl]);
            *(ushort4*)(Bt + (size_t)chunk * 2048 + (size_t)(by + nl) * 8) =
                *(const ushort4*)&o[0];
            *(ushort4*)(Bt + (size_t)chunk * 2048 + (size_t)(by + nl) * 8 + 4) =
                *(const ushort4*)&o[4];
        }
    } else if (b < PREP_WL) {
        // Wl reshuffle: B[n][k] = Wl[n][k]; block rel = chunk, thread = n.
        int chunk = b - PREP_W2;  // k8 in [0,32)
        int n = tidx;
        float4 f0 = *(const float4*)(Wl + (size_t)n * CD + chunk * 8);
        float4 f1 = *(const float4*)(Wl + (size_t)n * CD + chunk * 8 + 4);
        ushortT o[8];
        o[0] = f2b(f0.x); o[1] = f2b(f0.y); o[2] = f2b(f0.z); o[3] = f2b(f0.w);
        o[4] = f2b(f1.x); o[5] = f2b(f1.y); o[6] = f2b(f1.z); o[7] = f2b(f1.w);
        *(ushort4*)(Wlt + (size_t)chunk * 2048 + (size_t)n * 8) = *(const ushort4*)&o[0];
        *(ushort4*)(Wlt + (size_t)chunk * 2048 + (size_t)n * 8 + 4) = *(const ushort4*)&o[4];
    } else {
        // bucket scatter: srcs[d*64 + p] = src, p = atomicAdd(cnt[d]).
        int i = (b - PREP_WL) * 256 + tidx;
        if (i < EE) {
            int s = ei[i];
            int d = ei[EE + i];
            int p = atomicAdd(&cnt[d], 1);
            if (p < BCAP) srcs[((size_t)d << 6) + p] = s;
        } else if (i < ET) {
            int n = i - EE;
            int p = atomicAdd(&cnt[n], 1);
            if (p < BCAP) srcs[((size_t)n << 6) + p] = n;  // self loop
        }
    }
}

// ---------------- bf16 MFMA GEMM: C[M,256] = A[M,256] @ B^T -----------------
// LDS-FREE / BARRIER-FREE: B operands are loaded per-wave straight from
// L2 (Bf fragment-major layout written by prep). Straight-line kernel:
// 16 A-loads -> {4 B-loads, 8 MFMA} x8 -> store. No wave lockstep; latency
// hidden by TLP (LDS=0, ~115 VGPR -> 3-4 blocks/CU run asynchronously).
// Extra B read traffic ~200 MB aggregate from L2/L1 (B is 128 KB, hot).
// Block = 128 rows x 64 cols, grid 1568 = 8*196. XCD-aware bijective swizzle
// (round-3 verified): id = (bid&7)*196 + (bid>>3) -> 4 col-siblings of each
// row-group share one per-XCD L2, A fetched from HBM once.
// B-operand lane permutation preserved from the verified LDS version:
// mfma call j, lane l15 holds col bn + l15*4 + j, k-chunk kk*4+quad ->
// epilogue lane l15 owns 4 contiguous cols (colb = bn + l15*4).

template <int OUTF32>
__global__ __launch_bounds__(256, 3) void gemm_mfma(const ushortT* __restrict__ A,
                                                    const ushortT* __restrict__ Bf,
                                                    const float* __restrict__ bias,
                                                    float* __restrict__ outF,
                                                    ushortT* __restrict__ outB,
                                                    int M) {
    int tid = threadIdx.x;
    int wave = tid >> 6, lane = tid & 63;
    int wm = wave * 32;                    // wave's 32-row slice of 128-row block
    int bid = blockIdx.x;
    int id = (bid & 7) * 196 + (bid >> 3);  // XCD-aware bijective swizzle
    int bm = (id >> 2) * 128, bn = (id & 3) * 64;
    int l15 = lane & 15, quad = lane >> 4;

    // ---- A fragments: 16 independent 16B loads in flight ----
    bf16x8 a[2][8];
#pragma unroll
    for (int kk = 0; kk < 8; ++kk)
#pragma unroll
        for (int i = 0; i < 2; ++i)
            a[i][kk] = *(const bf16x8*)(A + (size_t)(bm + wm + i * 16 + l15) * CD + kk * 32 + quad * 8);

    f32x4 acc[2][4] = {};

    // ---- K loop: B direct from L2 (fragment-major), MFMA ----
#pragma unroll
    for (int kk = 0; kk < 8; ++kk) {
        int chunk = kk * 4 + quad;  // k-chunk index
        bf16x8 b[4];
#pragma unroll
        for (int j = 0; j < 4; ++j)
            b[j] = *(const bf16x8*)(Bf + (size_t)chunk * 2048 + (size_t)(bn + l15 * 4 + j) * 8);
#pragma unroll
        for (int i = 0; i < 2; ++i)
#pragma unroll
            for (int j = 0; j < 4; ++j)
                acc[i][j] = __builtin_amdgcn_mfma_f32_16x16x32_bf16(a[i][kk], b[j], acc[i][j], 0, 0, 0);
    }

    // ---- epilogue: lane l15 owns 4 contiguous cols bn+4*l15.. across j ----
    int colb = bn + l15 * 4;
#pragma unroll
    for (int i = 0; i < 2; ++i) {
#pragma unroll
        for (int r = 0; r < 4; ++r) {
            int row = bm + wm + i * 16 + quad * 4 + r;
            if (OUTF32) {
                if (row < M) {
                    float4 bv = *(const float4*)(bias + colb);
                    float4 v;
                    v.x = acc[i][0][r] + bv.x;
                    v.y = acc[i][1][r] + bv.y;
                    v.z = acc[i][2][r] + bv.z;
                    v.w = acc[i][3][r] + bv.w;
                    *(float4*)(outF + (size_t)row * CD + colb) = v;
                }
            } else {
                ushort4 o;
                o.x = f2b(acc[i][0][r]);
                o.y = f2b(acc[i][1][r]);
                o.z = f2b(acc[i][2][r]);
                o.w = f2b(acc[i][3][r]);
                *(ushort4*)(outB + (size_t)row * CD + colb) = o;  // ws padded
            }
        }
    }
}

// ---------------- GAT aggregation: TWO dst nodes per wave (32 lanes each) --
// Half-wave per node, lane owns 8 contiguous cols (16B loads/stores).
// Bucketed adjacency: rs = node<<6, deg = cnt[node].
// Latency-hiding order: issue the first 8 h-row gathers (addresses depend
// only on s_lane) BEFORE the softmax's as_-gather + shfl chain.
// ALPHA2=1: also emit next layer's alpha from the fp32 pre-cast row.

__device__ __forceinline__ float lrelu02(float x) { return x > 0.f ? x : 0.2f * x; }

template <int ALPHA2>
__global__ __launch_bounds__(256) void gat_agg(const ushortT* __restrict__ h,
                                               const float* __restrict__ as_,
                                               const float* __restrict__ ad_,
                                               const int* __restrict__ cnt,
                                               const int* __restrict__ srcs,
                                               const float* __restrict__ bias,
                                               ushortT* __restrict__ out,
                                               const float* __restrict__ w2s,
                                               const float* __restrict__ w2d,
                                               float* __restrict__ as_n,
                                               float* __restrict__ ad_n) {
    int node = blockIdx.x * 8 + (threadIdx.x >> 5);  // 8 nodes per 256-thread block
    int hl = threadIdx.x & 31;                       // lane within half-wave
    if (node >= NN) return;                          // NN % 8 == 0: never taken
    int deg = cnt[node];
    if (deg > BCAP) deg = BCAP;  // impossible for this input class; mem safety
    int rs = node << 6;
    float adst = ad_[node];

    float acc[8] = {0.f, 0.f, 0.f, 0.f, 0.f, 0.f, 0.f, 0.f};

    // pair-uniform max degree (branch must be wave-uniform)
    int maxdeg = max(deg, __shfl_xor(deg, 32));

    if (maxdeg <= 32) {
        int s_lane = srcs[rs + ((hl < deg) ? hl : 0)];

        // ---- issue first 8 row-gathers immediately (independent of softmax) ----
        int s0[8];
#pragma unroll
        for (int t = 0; t < 8; ++t) s0[t] = __shfl(s_lane, (t < deg) ? t : 0, 32);
        bf16x8 hv[8];
#pragma unroll
        for (int t = 0; t < 8; ++t)
            hv[t] = *(const bf16x8*)(h + (size_t)s0[t] * CD + hl * 8);

        // ---- softmax (runs under the gather latency) ----
        float e = (hl < deg) ? lrelu02(as_[s_lane] + adst) : -1e30f;
        float m = e;
#pragma unroll
        for (int off = 1; off < 32; off <<= 1) m = fmaxf(m, __shfl_xor(m, off));
        float ex = (hl < deg) ? __expf(e - m) : 0.f;
        float den = ex;
#pragma unroll
        for (int off = 1; off < 32; off <<= 1) den += __shfl_xor(den, off);
        float wl = ex / den;  // per-lane edge weight (0 for invalid lanes)

        // ---- apply weights to the first batch ----
#pragma unroll
        for (int t = 0; t < 8; ++t) {
            float wv = __shfl(wl, t, 32);
            wv = (t < deg) ? wv : 0.f;
#pragma unroll
            for (int c = 0; c < 8; ++c)
                acc[c] += wv * b2f((ushortT)hv[t][c]);
        }

        // ---- remaining batches (deg > 8; ~45% of pairs, usually 1 extra) ----
        for (int kk = 8; kk < maxdeg; kk += 8) {
            int s[8];
            float w[8];
#pragma unroll
            for (int t = 0; t < 8; ++t) {
                int idx = kk + t;                // wave-uniform
                int ii = (idx < deg) ? idx : 0;  // clamp per half (uniform there)
                int sv = __shfl(s_lane, ii, 32);
                float wv = __shfl(wl, ii, 32);
                s[t] = sv;
                w[t] = (idx < deg) ? wv : 0.f;
            }
            bf16x8 hv2[8];
#pragma unroll
            for (int t = 0; t < 8; ++t)
                hv2[t] = *(const bf16x8*)(h + (size_t)s[t] * CD + hl * 8);
#pragma unroll
            for (int t = 0; t < 8; ++t) {
#pragma unroll
                for (int c = 0; c < 8; ++c)
                    acc[c] += w[t] * b2f((ushortT)hv2[t][c]);
            }
        }
    } else {
        // ---- generic path (pair maxdeg > 32): 32-lane strided loops ----
        int re = rs + deg;
        float m = -1e30f;
        for (int k = rs + hl; k < re; k += 32) {
            float e = lrelu02(as_[srcs[k]] + adst);
            m = fmaxf(m, e);
        }
#pragma unroll
        for (int off = 1; off < 32; off <<= 1) m = fmaxf(m, __shfl_xor(m, off));
        float den = 0.f;
        for (int k = rs + hl; k < re; k += 32) {
            float e = lrelu02(as_[srcs[k]] + adst);
            den += __expf(e - m);
        }
#pragma unroll
        for (int off = 1; off < 32; off <<= 1) den += __shfl_xor(den, off);
        float inv_den = 1.f / den;
        for (int k = rs; k < re; ++k) {
            int sv = srcs[k];
            float e = lrelu02(as_[sv] + adst);
            float wv = __expf(e - m) * inv_den;
            bf16x8 hv = *(const bf16x8*)(h + (size_t)sv * CD + hl * 8);
#pragma unroll
            for (int c = 0; c < 8; ++c)
                acc[c] += wv * b2f((ushortT)hv[c]);
        }
    }

    // ---- epilogue: bias + relu (both convs feed relu), bf16 store ----
    float4 bv0 = *(const float4*)(bias + hl * 8);
    float4 bv1 = *(const float4*)(bias + hl * 8 + 4);
    float r[8];
    r[0] = fmaxf(acc[0] + bv0.x, 0.f);
    r[1] = fmaxf(acc[1] + bv0.y, 0.f);
    r[2] = fmaxf(acc[2] + bv0.z, 0.f);
    r[3] = fmaxf(acc[3] + bv0.w, 0.f);
    r[4] = fmaxf(acc[4] + bv1.x, 0.f);
    r[5] = fmaxf(acc[5] + bv1.y, 0.f);
    r[6] = fmaxf(acc[6] + bv1.z, 0.f);
    r[7] = fmaxf(acc[7] + bv1.w, 0.f);
    bf16x8 o;
#pragma unroll
    for (int c = 0; c < 8; ++c) o[c] = (short)f2b(r[c]);
    *(bf16x8*)(out + (size_t)node * CD + hl * 8) = o;

    if (ALPHA2) {
        float4 s0 = *(const float4*)(w2s + hl * 8);
        float4 s1 = *(const float4*)(w2s + hl * 8 + 4);
        float4 d0 = *(const float4*)(w2d + hl * 8);
        float4 d1 = *(const float4*)(w2d + hl * 8 + 4);
        float ss = r[0] * s0.x + r[1] * s0.y + r[2] * s0.z + r[3] * s0.w +
                   r[4] * s1.x + r[5] * s1.y + r[6] * s1.z + r[7] * s1.w;
        float dd = r[0] * d0.x + r[1] * d0.y + r[2] * d0.z + r[3] * d0.w +
                   r[4] * d1.x + r[5] * d1.y + r[6] * d1.z + r[7] * d1.w;
#pragma unroll
        for (int off = 1; off < 32; off <<= 1) {
            ss += __shfl_xor(ss, off);
            dd += __shfl_xor(dd, off);
        }
        if (hl == 0) {
            as_n[node] = ss;
            ad_n[node] = dd;
        }
    }
}

// ---------------- launch ----------------

extern "C" void kernel_launch(void* const* d_in, const int* in_sizes, int n_in,
                              void* d_out, int out_size, void* d_ws, size_t ws_size,
                              hipStream_t stream) {
    const float* x = (const float*)d_in[0];
    const int* ei = (const int*)d_in[1];
    const float* W1 = (const float*)d_in[2];
    const float* a1s = (const float*)d_in[3];
    const float* a1d = (const float*)d_in[4];
    const float* b1 = (const float*)d_in[5];
    const float* W2 = (const float*)d_in[6];
    const float* a2s = (const float*)d_in[7];
    const float* a2d = (const float*)d_in[8];
    const float* b2 = (const float*)d_in[9];
    const float* Wl = (const float*)d_in[10];
    const float* bl = (const float*)d_in[11];
    float* out = (float*)d_out;

    char* w = (char*)d_ws;
    ushortT* B0 = (ushortT*)w; w += (size_t)PAD_M * CD * 2;
    ushortT* B1 = (ushortT*)w; w += (size_t)PAD_M * CD * 2;
    ushortT* B2 = (ushortT*)w; w += (size_t)PAD_M * CD * 2;
    ushortT* W1t = (ushortT*)w; w += (size_t)CD * CD * 2;
    ushortT* W2t = (ushortT*)w; w += (size_t)CD * CD * 2;
    ushortT* Wlt = (ushortT*)w; w += (size_t)CD * CD * 2;
    float* as1 = (float*)w; w += (size_t)NN * 4;
    float* ad1 = (float*)w; w += (size_t)NN * 4;
    float* as2 = (float*)w; w += (size_t)NN * 4;
    float* ad2 = (float*)w; w += (size_t)NN * 4;
    float* w1s = (float*)w; w += CD * 4;
    float* w1d = (float*)w; w += CD * 4;
    float* w2s = (float*)w; w += CD * 4;
    float* w2d = (float*)w; w += CD * 4;
    int* cnt = (int*)w; w += (size_t)NN * 4;
    int* srcs = (int*)w; w += (size_t)NN * BCAP * 4;  // 12.8 MB buckets

    // alpha-vector precompute + bucket-counter zeroing (first kernel)
    wvec_kernel<<<128, 256, 0, stream>>>(W1, a1s, a1d, W2, a2s, a2d,
                                         w1s, w1d, w2s, w2d, cnt);

    // fused preprocessing: x cast + alpha1, W fragment transforms, bucket scatter
    prep_kernel<<<PREP_END, 256, 0, stream>>>(x, W1, W2, Wl, B0, W1t, W2t, Wlt,
                                              w1s, w1d, as1, ad1, ei, cnt, srcs);

    int ggrid = (PAD_M / 128) * 4;       // 1568 blocks of 128 rows x 64 cols
    int nagg_blocks = (NN + 7) / 8;      // 6250 blocks, 2 nodes per wave

    // Layer 1
    gemm_mfma<0><<<ggrid, 256, 0, stream>>>(B0, W1t, nullptr, nullptr, B1, NN);
    gat_agg<1><<<nagg_blocks, 256, 0, stream>>>(B1, as1, ad1, cnt, srcs,
                                                b1, B2, w2s, w2d, as2, ad2);

    // Layer 2
    gemm_mfma<0><<<ggrid, 256, 0, stream>>>(B2, W2t, nullptr, nullptr, B1, NN);
    gat_agg<0><<<nagg_blocks, 256, 0, stream>>>(B1, as2, ad2, cnt, srcs,
                                                b2, B0, nullptr, nullptr,
                                                nullptr, nullptr);

    // Final linear: out = B0 @ Wlt^T + bl (fp32 out)
    gemm_mfma<1><<<ggrid, 256, 0, stream>>>(B0, Wlt, bl, out, nullptr, NN);
}

// Round 8
// 268.939 us; speedup vs baseline: 1.0982x; 1.0982x over previous
//
#include <hip/hip_runtime.h>

#define NN 50000
#define EE 300000
#define ET (EE + NN)   // edges + self loops = 350000
#define CD 256
#define PAD_M 50176    // 392 * 128, covers gemm tile over-read
#define BCAP 64        // per-node src bucket capacity (max deg ~25, P(>63)<1e-30)

typedef unsigned short ushortT;
typedef short bf16x8 __attribute__((ext_vector_type(8)));
typedef float f32x4 __attribute__((ext_vector_type(4)));

__device__ __forceinline__ ushortT f2b(float f) {
    unsigned u = __builtin_bit_cast(unsigned, f);
    unsigned r = (u + 0x7FFFu + ((u >> 16) & 1u)) >> 16;
    return (ushortT)r;
}
__device__ __forceinline__ float b2f(ushortT b) {
    return __builtin_bit_cast(float, ((unsigned)b) << 16);
}

// ---------------- alpha-vector precompute: wXs = W @ a_src (row dots) ------
// (x@W)·a == x·(W@a): alpha1 is computed inside gemm1 (x already in
// registers there) and alpha2 in agg1's epilogue (fp32 acc in registers).
// grid 128: blocks [0,64) -> W1 rows, [64,128) -> W2 rows; wave per row.
// Also zeroes the bucket counters cnt[0..NN) (prep's scatter section, next
// kernel on the stream, consumes them).

__global__ __launch_bounds__(256) void wvec_kernel(
    const float* __restrict__ W1, const float* __restrict__ a1s,
    const float* __restrict__ a1d, const float* __restrict__ W2,
    const float* __restrict__ a2s, const float* __restrict__ a2d,
    float* __restrict__ w1s, float* __restrict__ w1d,
    float* __restrict__ w2s, float* __restrict__ w2d,
    int* __restrict__ cnt) {
    int b = blockIdx.x;
    // bucket-counter zeroing: 128*256 = 32768 threads cover 50000 ints in 2 steps
    int g = b * 256 + threadIdx.x;
    if (g < NN) cnt[g] = 0;
    if (g + 32768 < NN) cnt[g + 32768] = 0;

    const float* W = (b < 64) ? W1 : W2;
    const float* vs = (b < 64) ? a1s : a2s;
    const float* vd = (b < 64) ? a1d : a2d;
    float* os = (b < 64) ? w1s : w2s;
    float* od = (b < 64) ? w1d : w2d;
    int r = (b & 63) * 4 + (threadIdx.x >> 6);
    int lane = threadIdx.x & 63;
    float4 wv = *(const float4*)(W + (size_t)r * CD + lane * 4);
    float4 s4 = *(const float4*)(vs + lane * 4);
    float4 d4 = *(const float4*)(vd + lane * 4);
    float ss = wv.x * s4.x + wv.y * s4.y + wv.z * s4.z + wv.w * s4.w;
    float dd = wv.x * d4.x + wv.y * d4.y + wv.z * d4.z + wv.w * d4.w;
#pragma unroll
    for (int off = 1; off < 64; off <<= 1) {
        ss += __shfl_xor(ss, off);
        dd += __shfl_xor(dd, off);
    }
    if (lane == 0) {
        os[r] = ss;
        od[r] = dd;
    }
}

// ---------------- preprocessing (x-pass ELIMINATED — fused into gemm1) -----
// [0,64)       transpose-cast W1 -> W1t   (Bt[n][k] = W[k][n], bf16)
// [64,128)     transpose-cast W2 -> W2t
// [128,192)    straight-cast  Wl -> Wlt
// [192,1560)   bucket scatter: srcs[d*64+p] = src, p = atomicAdd(cnt[d])
//              (cnt zeroed by wvec; max deg ~25, stores clamped at BCAP)
#define PREP_W1 64
#define PREP_W2 128
#define PREP_WL 192
#define PREP_END 1560

__global__ __launch_bounds__(256) void prep_kernel(
    const float* __restrict__ W1, const float* __restrict__ W2,
    const float* __restrict__ Wl, ushortT* __restrict__ W1t,
    ushortT* __restrict__ W2t, ushortT* __restrict__ Wlt,
    const int* __restrict__ ei, int* __restrict__ cnt,
    int* __restrict__ srcs) {
    __shared__ float t[32][33];
    int b = blockIdx.x, tidx = threadIdx.x;
    if (b < PREP_W2) {
        const float* W = (b < PREP_W1) ? W1 : W2;
        ushortT* Bt = (b < PREP_W1) ? W1t : W2t;
        int rel = b - ((b < PREP_W1) ? 0 : PREP_W1);
        int bx = (rel & 7) * 32;   // k base
        int by = (rel >> 3) * 32;  // n base
        int xx = tidx & 31, yy = tidx >> 5;
        for (int y = yy; y < 32; y += 8) t[y][xx] = W[(size_t)(bx + y) * CD + by + xx];
        __syncthreads();
        for (int y = yy; y < 32; y += 8)
            Bt[(size_t)(by + y) * CD + bx + xx] = f2b(t[xx][y]);
    } else if (b < PREP_WL) {
        int id = (b - PREP_W2) * 256 + tidx;
        float4 v = *(const float4*)(Wl + (size_t)id * 4);
        ushort4 o;
        o.x = f2b(v.x); o.y = f2b(v.y); o.z = f2b(v.z); o.w = f2b(v.w);
        *(ushort4*)(Wlt + (size_t)id * 4) = o;
    } else {
        int i = (b - PREP_WL) * 256 + tidx;
        if (i < EE) {
            int s = ei[i];
            int d = ei[EE + i];
            int p = atomicAdd(&cnt[d], 1);
            if (p < BCAP) srcs[((size_t)d << 6) + p] = s;
        } else if (i < ET) {
            int n = i - EE;
            int p = atomicAdd(&cnt[n], 1);
            if (p < BCAP) srcs[((size_t)n << 6) + p] = n;  // self loop
        }
    }
}

// ---------------- bf16 MFMA GEMM: C[M,256] = A[M,256] @ Bt^T ----------------
// Block = 128 rows x 64 cols, 1-D grid 1568. XCD-aware bijective swizzle
// (1568 = 8*196): id = (bid&7)*196 + (bid>>3) -> the 4 col-siblings (same bm)
// land on ONE per-XCD L2, so A-rows are fetched from HBM once (round-3
// verified: -12 us; round-6's LDS-free variant REGRESSED — keep the
// global_load_lds staging + single barrier structure).
// B LDS layout: column-permuted (slot n -> col (n&15)*4+(n>>4)) so lane l15
// owns 4 contiguous output cols -> packed stores; 16B-chunk xor swizzle for
// bank conflicts (measured 0).

template <int OUTF32>
__global__ __launch_bounds__(256, 4) void gemm_mfma(const ushortT* __restrict__ A,
                                                    const ushortT* __restrict__ Bt,
                                                    const float* __restrict__ bias,
                                                    float* __restrict__ outF,
                                                    ushortT* __restrict__ outB,
                                                    int M) {
    __shared__ ushortT Bs[64 * 256];  // 32 KB
    int tid = threadIdx.x;
    int wave = tid >> 6, lane = tid & 63;
    int wm = wave * 32;                    // wave's 32-row slice of 128-row block
    int bid = blockIdx.x;
    int id = (bid & 7) * 196 + (bid >> 3);  // XCD-aware bijective swizzle
    int bm = (id >> 2) * 128, bn = (id & 3) * 64;
    int l15 = lane & 15, quad = lane >> 4;

    // ---- B staging: 64 slots x 32 chunks = 2048 16B chunks, 8 rounds ----
#pragma unroll
    for (int p = 0; p < 8; ++p) {
        int c = p * 256 + tid;             // lane-linear flat chunk id
        int slot = c >> 5;                 // LDS slot (permuted col)
        int piece = c & 31;
        int col = (slot & 15) * 4 + (slot >> 4);   // actual col for this slot
        int spiece = piece ^ (slot & 31);  // physical chunk p holds data chunk p^slot
        const ushortT* gb = Bt + (size_t)(bn + col) * CD + spiece * 8;
        __builtin_amdgcn_global_load_lds(
            (const __attribute__((address_space(1))) void*)gb,
            (__attribute__((address_space(3))) void*)(Bs + (size_t)(p * 256 + wave * 64) * 8),
            16, 0, 0);
    }

    // ---- hoist ALL A fragments (16 independent 16B loads in flight) ----
    bf16x8 a[2][8];
#pragma unroll
    for (int kk = 0; kk < 8; ++kk)
#pragma unroll
        for (int i = 0; i < 2; ++i)
            a[i][kk] = *(const bf16x8*)(A + (size_t)(bm + wm + i * 16 + l15) * CD + kk * 32 + quad * 8);

    __syncthreads();

    f32x4 acc[2][4] = {};

    // ---- K loop: pure LDS + MFMA ----
#pragma unroll
    for (int kk = 0; kk < 8; ++kk) {
        bf16x8 b[4];
        int kc = kk * 4 + quad;  // data chunk index within slot
#pragma unroll
        for (int j = 0; j < 4; ++j) {
            int slot = j * 16 + l15;
            b[j] = *(const bf16x8*)(Bs + (size_t)slot * 256 + (size_t)(kc ^ (slot & 31)) * 8);
        }
#pragma unroll
        for (int i = 0; i < 2; ++i)
#pragma unroll
            for (int j = 0; j < 4; ++j)
                acc[i][j] = __builtin_amdgcn_mfma_f32_16x16x32_bf16(a[i][kk], b[j], acc[i][j], 0, 0, 0);
    }

    // ---- epilogue: lane l15 owns 4 contiguous cols bn+4*l15.. across j ----
    int colb = bn + l15 * 4;
#pragma unroll
    for (int i = 0; i < 2; ++i) {
#pragma unroll
        for (int r = 0; r < 4; ++r) {
            int row = bm + wm + i * 16 + quad * 4 + r;
            if (OUTF32) {
                if (row < M) {
                    float4 bv = *(const float4*)(bias + colb);
                    float4 v;
                    v.x = acc[i][0][r] + bv.x;
                    v.y = acc[i][1][r] + bv.y;
                    v.z = acc[i][2][r] + bv.z;
                    v.w = acc[i][3][r] + bv.w;
                    *(float4*)(outF + (size_t)row * CD + colb) = v;
                }
            } else {
                ushort4 o;
                o.x = f2b(acc[i][0][r]);
                o.y = f2b(acc[i][1][r]);
                o.z = f2b(acc[i][2][r]);
                o.w = f2b(acc[i][3][r]);
                *(ushort4*)(outB + (size_t)row * CD + colb) = o;  // ws padded
            }
        }
    }
}

// ---------------- gemm1 variant: fp32 A (= x), in-register bf16 cast, and
// alpha1 = x·w1s / x·w1d computed during the fragment loads (bn==0 blocks
// hold full rows; reduce over the 4 k-quads with 2 shfl_xor). Removes the
// entire prep x-pass (~40 us: 77 MB + 12-deep ds_bpermute chains) at the
// cost of reading x as fp32. Round-2's version of this REGRESSED because the
// 4 col-siblings re-fetched fp32 A across 4 different XCD L2s (FETCH=100MB);
// the XCD swizzle (round-3 verified mechanism) makes the siblings L2-hit.

__global__ __launch_bounds__(256, 2) void gemm_mfma_x(
    const float* __restrict__ A, const ushortT* __restrict__ Bt,
    ushortT* __restrict__ outB, const float* __restrict__ w1s,
    const float* __restrict__ w1d, float* __restrict__ as1,
    float* __restrict__ ad1) {
    __shared__ ushortT Bs[64 * 256];  // 32 KB
    int tid = threadIdx.x;
    int wave = tid >> 6, lane = tid & 63;
    int wm = wave * 32;
    int bid = blockIdx.x;
    int id = (bid & 7) * 196 + (bid >> 3);  // XCD-aware bijective swizzle
    int bm = (id >> 2) * 128, bn = (id & 3) * 64;
    int l15 = lane & 15, quad = lane >> 4;

    // ---- B staging (identical to gemm_mfma) ----
#pragma unroll
    for (int p = 0; p < 8; ++p) {
        int c = p * 256 + tid;
        int slot = c >> 5;
        int piece = c & 31;
        int col = (slot & 15) * 4 + (slot >> 4);
        int spiece = piece ^ (slot & 31);
        const ushortT* gb = Bt + (size_t)(bn + col) * CD + spiece * 8;
        __builtin_amdgcn_global_load_lds(
            (const __attribute__((address_space(1))) void*)gb,
            (__attribute__((address_space(3))) void*)(Bs + (size_t)(p * 256 + wave * 64) * 8),
            16, 0, 0);
    }

    // ---- fp32 A fragment loads + cast + (bn==0) alpha1 partial dots ----
    int r0 = bm + wm + l15;
    int r1 = r0 + 16;
    const float* A0 = A + (size_t)((r0 < NN) ? r0 : (NN - 1)) * CD;  // x has no pad
    const float* A1 = A + (size_t)((r1 < NN) ? r1 : (NN - 1)) * CD;
    bool doA = (bn == 0);
    float ss0 = 0.f, sd0 = 0.f, ss1 = 0.f, sd1 = 0.f;

    bf16x8 a[2][8];
#pragma unroll
    for (int kk = 0; kk < 8; ++kk) {
        int cb = kk * 32 + quad * 8;
        float4 f00 = *(const float4*)(A0 + cb);
        float4 f01 = *(const float4*)(A0 + cb + 4);
        float4 f10 = *(const float4*)(A1 + cb);
        float4 f11 = *(const float4*)(A1 + cb + 4);
        bf16x8 v0, v1;
        v0[0] = (short)f2b(f00.x); v0[1] = (short)f2b(f00.y);
        v0[2] = (short)f2b(f00.z); v0[3] = (short)f2b(f00.w);
        v0[4] = (short)f2b(f01.x); v0[5] = (short)f2b(f01.y);
        v0[6] = (short)f2b(f01.z); v0[7] = (short)f2b(f01.w);
        v1[0] = (short)f2b(f10.x); v1[1] = (short)f2b(f10.y);
        v1[2] = (short)f2b(f10.z); v1[3] = (short)f2b(f10.w);
        v1[4] = (short)f2b(f11.x); v1[5] = (short)f2b(f11.y);
        v1[6] = (short)f2b(f11.z); v1[7] = (short)f2b(f11.w);
        a[0][kk] = v0;
        a[1][kk] = v1;
        if (doA) {
            float4 ws0 = *(const float4*)(w1s + cb);
            float4 ws1 = *(const float4*)(w1s + cb + 4);
            float4 wd0 = *(const float4*)(w1d + cb);
            float4 wd1 = *(const float4*)(w1d + cb + 4);
            ss0 += f00.x * ws0.x + f00.y * ws0.y + f00.z * ws0.z + f00.w * ws0.w +
                   f01.x * ws1.x + f01.y * ws1.y + f01.z * ws1.z + f01.w * ws1.w;
            sd0 += f00.x * wd0.x + f00.y * wd0.y + f00.z * wd0.z + f00.w * wd0.w +
                   f01.x * wd1.x + f01.y * wd1.y + f01.z * wd1.z + f01.w * wd1.w;
            ss1 += f10.x * ws0.x + f10.y * ws0.y + f10.z * ws0.z + f10.w * ws0.w +
                   f11.x * ws1.x + f11.y * ws1.y + f11.z * ws1.z + f11.w * ws1.w;
            sd1 += f10.x * wd0.x + f10.y * wd0.y + f10.z * wd0.z + f10.w * wd0.w +
                   f11.x * wd1.x + f11.y * wd1.y + f11.z * wd1.z + f11.w * wd1.w;
        }
    }

    if (doA) {
#pragma unroll
        for (int off = 16; off < 64; off <<= 1) {
            ss0 += __shfl_xor(ss0, off);
            sd0 += __shfl_xor(sd0, off);
            ss1 += __shfl_xor(ss1, off);
            sd1 += __shfl_xor(sd1, off);
        }
        if (lane < 16) {
            if (r0 < NN) { as1[r0] = ss0; ad1[r0] = sd0; }
            if (r1 < NN) { as1[r1] = ss1; ad1[r1] = sd1; }
        }
    }

    __syncthreads();

    f32x4 acc[2][4] = {};

#pragma unroll
    for (int kk = 0; kk < 8; ++kk) {
        bf16x8 b[4];
        int kc = kk * 4 + quad;
#pragma unroll
        for (int j = 0; j < 4; ++j) {
            int slot = j * 16 + l15;
            b[j] = *(const bf16x8*)(Bs + (size_t)slot * 256 + (size_t)(kc ^ (slot & 31)) * 8);
        }
#pragma unroll
        for (int i = 0; i < 2; ++i)
#pragma unroll
            for (int j = 0; j < 4; ++j)
                acc[i][j] = __builtin_amdgcn_mfma_f32_16x16x32_bf16(a[i][kk], b[j], acc[i][j], 0, 0, 0);
    }

    int colb = bn + l15 * 4;
#pragma unroll
    for (int i = 0; i < 2; ++i) {
#pragma unroll
        for (int r = 0; r < 4; ++r) {
            int row = bm + wm + i * 16 + quad * 4 + r;
            ushort4 o;
            o.x = f2b(acc[i][0][r]);
            o.y = f2b(acc[i][1][r]);
            o.z = f2b(acc[i][2][r]);
            o.w = f2b(acc[i][3][r]);
            *(ushort4*)(outB + (size_t)row * CD + colb) = o;  // ws padded
        }
    }
}

// ---------------- GAT aggregation: TWO dst nodes per wave (32 lanes each) --
// Half-wave per node, lane owns 8 contiguous cols (16B loads/stores).
// Bucketed adjacency: rs = node<<6, deg = cnt[node].
// Latency-hiding order: issue the first 8 h-row gathers (addresses depend
// only on s_lane) BEFORE the softmax's as_-gather + shfl chain.
// ALPHA2=1: also emit next layer's alpha from the fp32 pre-cast row.

__device__ __forceinline__ float lrelu02(float x) { return x > 0.f ? x : 0.2f * x; }

template <int ALPHA2>
__global__ __launch_bounds__(256) void gat_agg(const ushortT* __restrict__ h,
                                               const float* __restrict__ as_,
                                               const float* __restrict__ ad_,
                                               const int* __restrict__ cnt,
                                               const int* __restrict__ srcs,
                                               const float* __restrict__ bias,
                                               ushortT* __restrict__ out,
                                               const float* __restrict__ w2s,
                                               const float* __restrict__ w2d,
                                               float* __restrict__ as_n,
                                               float* __restrict__ ad_n) {
    int node = blockIdx.x * 8 + (threadIdx.x >> 5);  // 8 nodes per 256-thread block
    int hl = threadIdx.x & 31;                       // lane within half-wave
    if (node >= NN) return;                          // NN % 8 == 0: never taken
    int deg = cnt[node];
    if (deg > BCAP) deg = BCAP;  // impossible for this input class; mem safety
    int rs = node << 6;
    float adst = ad_[node];

    float acc[8] = {0.f, 0.f, 0.f, 0.f, 0.f, 0.f, 0.f, 0.f};

    // pair-uniform max degree (branch must be wave-uniform)
    int maxdeg = max(deg, __shfl_xor(deg, 32));

    if (maxdeg <= 32) {
        int s_lane = srcs[rs + ((hl < deg) ? hl : 0)];

        // ---- issue first 8 row-gathers immediately (independent of softmax) ----
        int s0[8];
#pragma unroll
        for (int t = 0; t < 8; ++t) s0[t] = __shfl(s_lane, (t < deg) ? t : 0, 32);
        bf16x8 hv[8];
#pragma unroll
        for (int t = 0; t < 8; ++t)
            hv[t] = *(const bf16x8*)(h + (size_t)s0[t] * CD + hl * 8);

        // ---- softmax (runs under the gather latency) ----
        float e = (hl < deg) ? lrelu02(as_[s_lane] + adst) : -1e30f;
        float m = e;
#pragma unroll
        for (int off = 1; off < 32; off <<= 1) m = fmaxf(m, __shfl_xor(m, off));
        float ex = (hl < deg) ? __expf(e - m) : 0.f;
        float den = ex;
#pragma unroll
        for (int off = 1; off < 32; off <<= 1) den += __shfl_xor(den, off);
        float wl = ex / den;  // per-lane edge weight (0 for invalid lanes)

        // ---- apply weights to the first batch ----
#pragma unroll
        for (int t = 0; t < 8; ++t) {
            float wv = __shfl(wl, t, 32);
            wv = (t < deg) ? wv : 0.f;
#pragma unroll
            for (int c = 0; c < 8; ++c)
                acc[c] += wv * b2f((ushortT)hv[t][c]);
        }

        // ---- remaining batches (deg > 8; ~45% of pairs, usually 1 extra) ----
        for (int kk = 8; kk < maxdeg; kk += 8) {
            int s[8];
            float w[8];
#pragma unroll
            for (int t = 0; t < 8; ++t) {
                int idx = kk + t;                // wave-uniform
                int ii = (idx < deg) ? idx : 0;  // clamp per half (uniform there)
                int sv = __shfl(s_lane, ii, 32);
                float wv = __shfl(wl, ii, 32);
                s[t] = sv;
                w[t] = (idx < deg) ? wv : 0.f;
            }
            bf16x8 hv2[8];
#pragma unroll
            for (int t = 0; t < 8; ++t)
                hv2[t] = *(const bf16x8*)(h + (size_t)s[t] * CD + hl * 8);
#pragma unroll
            for (int t = 0; t < 8; ++t) {
#pragma unroll
                for (int c = 0; c < 8; ++c)
                    acc[c] += w[t] * b2f((ushortT)hv2[t][c]);
            }
        }
    } else {
        // ---- generic path (pair maxdeg > 32): 32-lane strided loops ----
        int re = rs + deg;
        float m = -1e30f;
        for (int k = rs + hl; k < re; k += 32) {
            float e = lrelu02(as_[srcs[k]] + adst);
            m = fmaxf(m, e);
        }
#pragma unroll
        for (int off = 1; off < 32; off <<= 1) m = fmaxf(m, __shfl_xor(m, off));
        float den = 0.f;
        for (int k = rs + hl; k < re; k += 32) {
            float e = lrelu02(as_[srcs[k]] + adst);
            den += __expf(e - m);
        }
#pragma unroll
        for (int off = 1; off < 32; off <<= 1) den += __shfl_xor(den, off);
        float inv_den = 1.f / den;
        for (int k = rs; k < re; ++k) {
            int sv = srcs[k];
            float e = lrelu02(as_[sv] + adst);
            float wv = __expf(e - m) * inv_den;
            bf16x8 hv = *(const bf16x8*)(h + (size_t)sv * CD + hl * 8);
#pragma unroll
            for (int c = 0; c < 8; ++c)
                acc[c] += wv * b2f((ushortT)hv[c]);
        }
    }

    // ---- epilogue: bias + relu (both convs feed relu), bf16 store ----
    float4 bv0 = *(const float4*)(bias + hl * 8);
    float4 bv1 = *(const float4*)(bias + hl * 8 + 4);
    float r[8];
    r[0] = fmaxf(acc[0] + bv0.x, 0.f);
    r[1] = fmaxf(acc[1] + bv0.y, 0.f);
    r[2] = fmaxf(acc[2] + bv0.z, 0.f);
    r[3] = fmaxf(acc[3] + bv0.w, 0.f);
    r[4] = fmaxf(acc[4] + bv1.x, 0.f);
    r[5] = fmaxf(acc[5] + bv1.y, 0.f);
    r[6] = fmaxf(acc[6] + bv1.z, 0.f);
    r[7] = fmaxf(acc[7] + bv1.w, 0.f);
    bf16x8 o;
#pragma unroll
    for (int c = 0; c < 8; ++c) o[c] = (short)f2b(r[c]);
    *(bf16x8*)(out + (size_t)node * CD + hl * 8) = o;

    if (ALPHA2) {
        float4 s0 = *(const float4*)(w2s + hl * 8);
        float4 s1 = *(const float4*)(w2s + hl * 8 + 4);
        float4 d0 = *(const float4*)(w2d + hl * 8);
        float4 d1 = *(const float4*)(w2d + hl * 8 + 4);
        float ss = r[0] * s0.x + r[1] * s0.y + r[2] * s0.z + r[3] * s0.w +
                   r[4] * s1.x + r[5] * s1.y + r[6] * s1.z + r[7] * s1.w;
        float dd = r[0] * d0.x + r[1] * d0.y + r[2] * d0.z + r[3] * d0.w +
                   r[4] * d1.x + r[5] * d1.y + r[6] * d1.z + r[7] * d1.w;
#pragma unroll
        for (int off = 1; off < 32; off <<= 1) {
            ss += __shfl_xor(ss, off);
            dd += __shfl_xor(dd, off);
        }
        if (hl == 0) {
            as_n[node] = ss;
            ad_n[node] = dd;
        }
    }
}

// ---------------- launch ----------------

extern "C" void kernel_launch(void* const* d_in, const int* in_sizes, int n_in,
                              void* d_out, int out_size, void* d_ws, size_t ws_size,
                              hipStream_t stream) {
    const float* x = (const float*)d_in[0];
    const int* ei = (const int*)d_in[1];
    const float* W1 = (const float*)d_in[2];
    const float* a1s = (const float*)d_in[3];
    const float* a1d = (const float*)d_in[4];
    const float* b1 = (const float*)d_in[5];
    const float* W2 = (const float*)d_in[6];
    const float* a2s = (const float*)d_in[7];
    const float* a2d = (const float*)d_in[8];
    const float* b2 = (const float*)d_in[9];
    const float* Wl = (const float*)d_in[10];
    const float* bl = (const float*)d_in[11];
    float* out = (float*)d_out;

    char* w = (char*)d_ws;
    ushortT* B0 = (ushortT*)w; w += (size_t)PAD_M * CD * 2;
    ushortT* B1 = (ushortT*)w; w += (size_t)PAD_M * CD * 2;
    ushortT* B2 = (ushortT*)w; w += (size_t)PAD_M * CD * 2;
    ushortT* W1t = (ushortT*)w; w += (size_t)CD * CD * 2;
    ushortT* W2t = (ushortT*)w; w += (size_t)CD * CD * 2;
    ushortT* Wlt = (ushortT*)w; w += (size_t)CD * CD * 2;
    float* as1 = (float*)w; w += (size_t)NN * 4;
    float* ad1 = (float*)w; w += (size_t)NN * 4;
    float* as2 = (float*)w; w += (size_t)NN * 4;
    float* ad2 = (float*)w; w += (size_t)NN * 4;
    float* w1s = (float*)w; w += CD * 4;
    float* w1d = (float*)w; w += CD * 4;
    float* w2s = (float*)w; w += CD * 4;
    float* w2d = (float*)w; w += CD * 4;
    int* cnt = (int*)w; w += (size_t)NN * 4;
    int* srcs = (int*)w; w += (size_t)NN * BCAP * 4;  // 12.8 MB buckets

    // alpha-vector precompute + bucket-counter zeroing (first kernel)
    wvec_kernel<<<128, 256, 0, stream>>>(W1, a1s, a1d, W2, a2s, a2d,
                                         w1s, w1d, w2s, w2d, cnt);

    // preprocessing: W transposes + Wl cast + bucket scatter (no x-pass)
    prep_kernel<<<PREP_END, 256, 0, stream>>>(W1, W2, Wl, W1t, W2t, Wlt,
                                              ei, cnt, srcs);

    int ggrid = (PAD_M / 128) * 4;       // 1568 blocks of 128 rows x 64 cols
    int nagg_blocks = (NN + 7) / 8;      // 6250 blocks, 2 nodes per wave

    // Layer 1: fused x-cast + alpha1 + GEMM (XCD-swizzled)
    gemm_mfma_x<<<ggrid, 256, 0, stream>>>(x, W1t, B1, w1s, w1d, as1, ad1);
    gat_agg<1><<<nagg_blocks, 256, 0, stream>>>(B1, as1, ad1, cnt, srcs,
                                                b1, B2, w2s, w2d, as2, ad2);

    // Layer 2
    gemm_mfma<0><<<ggrid, 256, 0, stream>>>(B2, W2t, nullptr, nullptr, B1, NN);
    gat_agg<0><<<nagg_blocks, 256, 0, stream>>>(B1, as2, ad2, cnt, srcs,
                                                b2, B0, nullptr, nullptr,
                                                nullptr, nullptr);

    // Final linear: out = B0 @ Wlt^T + bl (fp32 out)
    gemm_mfma<1><<<ggrid, 256, 0, stream>>>(B0, Wlt, bl, out, nullptr, NN);
}

// Round 9
// 264.039 us; speedup vs baseline: 1.1185x; 1.0186x over previous
//
#include <hip/hip_runtime.h>

#define NN 50000
#define EE 300000
#define ET (EE + NN)   // edges + self loops = 350000
#define CD 256
#define PAD_M 50176    // 392 * 128, covers gemm tile over-read
#define BCAP 64        // per-node src bucket capacity (max deg ~25, P(>63)<1e-30)

typedef unsigned short ushortT;
typedef short bf16x8 __attribute__((ext_vector_type(8)));
typedef float f32x4 __attribute__((ext_vector_type(4)));

__device__ __forceinline__ ushortT f2b(float f) {
    unsigned u = __builtin_bit_cast(unsigned, f);
    unsigned r = (u + 0x7FFFu + ((u >> 16) & 1u)) >> 16;
    return (ushortT)r;
}
__device__ __forceinline__ float b2f(ushortT b) {
    return __builtin_bit_cast(float, ((unsigned)b) << 16);
}

// ---------------- alpha-vector precompute: wXs = W @ a_src (row dots) ------
// (x@W)·a == x·(W@a): lets alpha1 be computed in prep (x in registers) and
// alpha2 in agg1's epilogue (fp32 acc in registers).
// grid 128: blocks [0,64) -> W1 rows, [64,128) -> W2 rows; wave per row.
// Also zeroes the bucket counters cnt[0..NN) (prep's scatter tail consumes).

__global__ __launch_bounds__(256) void wvec_kernel(
    const float* __restrict__ W1, const float* __restrict__ a1s,
    const float* __restrict__ a1d, const float* __restrict__ W2,
    const float* __restrict__ a2s, const float* __restrict__ a2d,
    float* __restrict__ w1s, float* __restrict__ w1d,
    float* __restrict__ w2s, float* __restrict__ w2d,
    int* __restrict__ cnt) {
    int b = blockIdx.x;
    // bucket-counter zeroing: 128*256 = 32768 threads cover 50000 ints in 2 steps
    int g = b * 256 + threadIdx.x;
    if (g < NN) cnt[g] = 0;
    if (g + 32768 < NN) cnt[g + 32768] = 0;

    const float* W = (b < 64) ? W1 : W2;
    const float* vs = (b < 64) ? a1s : a2s;
    const float* vd = (b < 64) ? a1d : a2d;
    float* os = (b < 64) ? w1s : w2s;
    float* od = (b < 64) ? w1d : w2d;
    int r = (b & 63) * 4 + (threadIdx.x >> 6);
    int lane = threadIdx.x & 63;
    float4 wv = *(const float4*)(W + (size_t)r * CD + lane * 4);
    float4 s4 = *(const float4*)(vs + lane * 4);
    float4 d4 = *(const float4*)(vd + lane * 4);
    float ss = wv.x * s4.x + wv.y * s4.y + wv.z * s4.z + wv.w * s4.w;
    float dd = wv.x * d4.x + wv.y * d4.y + wv.z * d4.z + wv.w * d4.w;
#pragma unroll
    for (int off = 1; off < 64; off <<= 1) {
        ss += __shfl_xor(ss, off);
        dd += __shfl_xor(dd, off);
    }
    if (lane == 0) {
        os[r] = ss;
        od[r] = dd;
    }
}

// ---------------- fused preprocessing ----------------
// x-pass restructured for latency: FOUR rows per wave (was one). Each lane
// issues 4 independent HBM loads (float4 from 4 rows) and the alpha reduce
// runs 8 interleaved shuffle chains (ss0-3,dd0-3) -> 8-wide ILP per step,
// 4x fewer serial block-rounds (12500 -> 3125 blocks). Round-6 counters
// showed the old 1-row/wave pass latency-bound at 1.6 TB/s, VALUBusy 12%.
// [0,3125)      x: cast->bf16 + alpha1, 16 rows/block (4 waves x 4 rows)
// [3125,3189)   transpose-cast W1 -> W1t
// [3189,3253)   transpose-cast W2 -> W2t
// [3253,3317)   straight-cast Wl -> Wlt
// [3317,4685)   bucket scatter (cnt zeroed by wvec; max deg ~25, clamped)
#define PREP_X 3125
#define PREP_W1 3189
#define PREP_W2 3253
#define PREP_WL 3317
#define PREP_END 4685

__global__ __launch_bounds__(256) void prep_kernel(
    const float* __restrict__ x, const float* __restrict__ W1,
    const float* __restrict__ W2, const float* __restrict__ Wl,
    ushortT* __restrict__ B0, ushortT* __restrict__ W1t,
    ushortT* __restrict__ W2t, ushortT* __restrict__ Wlt,
    const float* __restrict__ w1s, const float* __restrict__ w1d,
    float* __restrict__ as1, float* __restrict__ ad1,
    const int* __restrict__ ei, int* __restrict__ cnt,
    int* __restrict__ srcs) {
    __shared__ float t[32][33];
    int b = blockIdx.x, tidx = threadIdx.x;
    if (b < PREP_X) {
        int row0 = b * 16 + (tidx >> 6) * 4;  // wave's 4 rows
        int lane = tidx & 63;
        const float* xr = x + (size_t)row0 * CD + lane * 4;
        // 4 independent loads in flight
        float4 v0 = *(const float4*)(xr);
        float4 v1 = *(const float4*)(xr + CD);
        float4 v2 = *(const float4*)(xr + CD * 2);
        float4 v3 = *(const float4*)(xr + CD * 3);
        ushortT* br = B0 + (size_t)row0 * CD + lane * 4;
        ushort4 o0, o1, o2, o3;
        o0.x = f2b(v0.x); o0.y = f2b(v0.y); o0.z = f2b(v0.z); o0.w = f2b(v0.w);
        o1.x = f2b(v1.x); o1.y = f2b(v1.y); o1.z = f2b(v1.z); o1.w = f2b(v1.w);
        o2.x = f2b(v2.x); o2.y = f2b(v2.y); o2.z = f2b(v2.z); o2.w = f2b(v2.w);
        o3.x = f2b(v3.x); o3.y = f2b(v3.y); o3.z = f2b(v3.z); o3.w = f2b(v3.w);
        *(ushort4*)(br) = o0;
        *(ushort4*)(br + CD) = o1;
        *(ushort4*)(br + CD * 2) = o2;
        *(ushort4*)(br + CD * 3) = o3;
        float4 s4 = *(const float4*)(w1s + lane * 4);
        float4 d4 = *(const float4*)(w1d + lane * 4);
        float ss0 = v0.x * s4.x + v0.y * s4.y + v0.z * s4.z + v0.w * s4.w;
        float ss1 = v1.x * s4.x + v1.y * s4.y + v1.z * s4.z + v1.w * s4.w;
        float ss2 = v2.x * s4.x + v2.y * s4.y + v2.z * s4.z + v2.w * s4.w;
        float ss3 = v3.x * s4.x + v3.y * s4.y + v3.z * s4.z + v3.w * s4.w;
        float dd0 = v0.x * d4.x + v0.y * d4.y + v0.z * d4.z + v0.w * d4.w;
        float dd1 = v1.x * d4.x + v1.y * d4.y + v1.z * d4.z + v1.w * d4.w;
        float dd2 = v2.x * d4.x + v2.y * d4.y + v2.z * d4.z + v2.w * d4.w;
        float dd3 = v3.x * d4.x + v3.y * d4.y + v3.z * d4.z + v3.w * d4.w;
#pragma unroll
        for (int off = 1; off < 64; off <<= 1) {
            ss0 += __shfl_xor(ss0, off);
            ss1 += __shfl_xor(ss1, off);
            ss2 += __shfl_xor(ss2, off);
            ss3 += __shfl_xor(ss3, off);
            dd0 += __shfl_xor(dd0, off);
            dd1 += __shfl_xor(dd1, off);
            dd2 += __shfl_xor(dd2, off);
            dd3 += __shfl_xor(dd3, off);
        }
        if (lane == 0) {
            as1[row0] = ss0;     ad1[row0] = dd0;
            as1[row0 + 1] = ss1; ad1[row0 + 1] = dd1;
            as1[row0 + 2] = ss2; ad1[row0 + 2] = dd2;
            as1[row0 + 3] = ss3; ad1[row0 + 3] = dd3;
        }
    } else if (b < PREP_W2) {
        const float* W = (b < PREP_W1) ? W1 : W2;
        ushortT* Bt = (b < PREP_W1) ? W1t : W2t;
        int rel = b - ((b < PREP_W1) ? PREP_X : PREP_W1);
        int bx = (rel & 7) * 32;   // k base
        int by = (rel >> 3) * 32;  // n base
        int xx = tidx & 31, yy = tidx >> 5;
        for (int y = yy; y < 32; y += 8) t[y][xx] = W[(size_t)(bx + y) * CD + by + xx];
        __syncthreads();
        for (int y = yy; y < 32; y += 8)
            Bt[(size_t)(by + y) * CD + bx + xx] = f2b(t[xx][y]);
    } else if (b < PREP_WL) {
        int id = (b - PREP_W2) * 256 + tidx;
        float4 v = *(const float4*)(Wl + (size_t)id * 4);
        ushort4 o;
        o.x = f2b(v.x); o.y = f2b(v.y); o.z = f2b(v.z); o.w = f2b(v.w);
        *(ushort4*)(Wlt + (size_t)id * 4) = o;
    } else {
        int i = (b - PREP_WL) * 256 + tidx;
        if (i < EE) {
            int s = ei[i];
            int d = ei[EE + i];
            int p = atomicAdd(&cnt[d], 1);
            if (p < BCAP) srcs[((size_t)d << 6) + p] = s;
        } else if (i < ET) {
            int n = i - EE;
            int p = atomicAdd(&cnt[n], 1);
            if (p < BCAP) srcs[((size_t)n << 6) + p] = n;  // self loop
        }
    }
}

// ---------------- bf16 MFMA GEMM: C[M,256] = A[M,256] @ Bt^T ----------------
// Block = 128 rows x 64 cols, 1-D grid 1568. XCD-aware bijective swizzle
// (1568 = 8*196): id = (bid&7)*196 + (bid>>3) -> the 4 col-siblings (same bm)
// land on ONE per-XCD L2, so A-rows are fetched from HBM once (round-3
// verified; round-8 FETCH counters confirmed the mechanism directly).
// Keep global_load_lds staging + single barrier (round-6 LDS-free REGRESSED;
// round-4 256-row tile REGRESSED; round-8 fp32-A fusion REGRESSED).
// B LDS layout: column-permuted (slot n -> col (n&15)*4+(n>>4)) so lane l15
// owns 4 contiguous output cols -> packed stores; 16B-chunk xor swizzle for
// bank conflicts (measured 0).

template <int OUTF32>
__global__ __launch_bounds__(256, 4) void gemm_mfma(const ushortT* __restrict__ A,
                                                    const ushortT* __restrict__ Bt,
                                                    const float* __restrict__ bias,
                                                    float* __restrict__ outF,
                                                    ushortT* __restrict__ outB,
                                                    int M) {
    __shared__ ushortT Bs[64 * 256];  // 32 KB
    int tid = threadIdx.x;
    int wave = tid >> 6, lane = tid & 63;
    int wm = wave * 32;                    // wave's 32-row slice of 128-row block
    int bid = blockIdx.x;
    int id = (bid & 7) * 196 + (bid >> 3);  // XCD-aware bijective swizzle
    int bm = (id >> 2) * 128, bn = (id & 3) * 64;
    int l15 = lane & 15, quad = lane >> 4;

    // ---- B staging: 64 slots x 32 chunks = 2048 16B chunks, 8 rounds ----
#pragma unroll
    for (int p = 0; p < 8; ++p) {
        int c = p * 256 + tid;             // lane-linear flat chunk id
        int slot = c >> 5;                 // LDS slot (permuted col)
        int piece = c & 31;
        int col = (slot & 15) * 4 + (slot >> 4);   // actual col for this slot
        int spiece = piece ^ (slot & 31);  // physical chunk p holds data chunk p^slot
        const ushortT* gb = Bt + (size_t)(bn + col) * CD + spiece * 8;
        __builtin_amdgcn_global_load_lds(
            (const __attribute__((address_space(1))) void*)gb,
            (__attribute__((address_space(3))) void*)(Bs + (size_t)(p * 256 + wave * 64) * 8),
            16, 0, 0);
    }

    // ---- hoist ALL A fragments (16 independent 16B loads in flight) ----
    bf16x8 a[2][8];
#pragma unroll
    for (int kk = 0; kk < 8; ++kk)
#pragma unroll
        for (int i = 0; i < 2; ++i)
            a[i][kk] = *(const bf16x8*)(A + (size_t)(bm + wm + i * 16 + l15) * CD + kk * 32 + quad * 8);

    __syncthreads();

    f32x4 acc[2][4] = {};

    // ---- K loop: pure LDS + MFMA ----
#pragma unroll
    for (int kk = 0; kk < 8; ++kk) {
        bf16x8 b[4];
        int kc = kk * 4 + quad;  // data chunk index within slot
#pragma unroll
        for (int j = 0; j < 4; ++j) {
            int slot = j * 16 + l15;
            b[j] = *(const bf16x8*)(Bs + (size_t)slot * 256 + (size_t)(kc ^ (slot & 31)) * 8);
        }
#pragma unroll
        for (int i = 0; i < 2; ++i)
#pragma unroll
            for (int j = 0; j < 4; ++j)
                acc[i][j] = __builtin_amdgcn_mfma_f32_16x16x32_bf16(a[i][kk], b[j], acc[i][j], 0, 0, 0);
    }

    // ---- epilogue: lane l15 owns 4 contiguous cols bn+4*l15.. across j ----
    int colb = bn + l15 * 4;
#pragma unroll
    for (int i = 0; i < 2; ++i) {
#pragma unroll
        for (int r = 0; r < 4; ++r) {
            int row = bm + wm + i * 16 + quad * 4 + r;
            if (OUTF32) {
                if (row < M) {
                    float4 bv = *(const float4*)(bias + colb);
                    float4 v;
                    v.x = acc[i][0][r] + bv.x;
                    v.y = acc[i][1][r] + bv.y;
                    v.z = acc[i][2][r] + bv.z;
                    v.w = acc[i][3][r] + bv.w;
                    *(float4*)(outF + (size_t)row * CD + colb) = v;
                }
            } else {
                ushort4 o;
                o.x = f2b(acc[i][0][r]);
                o.y = f2b(acc[i][1][r]);
                o.z = f2b(acc[i][2][r]);
                o.w = f2b(acc[i][3][r]);
                *(ushort4*)(outB + (size_t)row * CD + colb) = o;  // ws padded
            }
        }
    }
}

// ---------------- GAT aggregation: TWO dst nodes per wave (32 lanes each) --
// Half-wave per node, lane owns 8 contiguous cols (16B loads/stores).
// Bucketed adjacency: rs = node<<6, deg = cnt[node].
// Latency-hiding order: issue the first 8 h-row gathers (addresses depend
// only on s_lane) BEFORE the softmax's as_-gather + shfl chain.
// ALPHA2=1: also emit next layer's alpha from the fp32 pre-cast row.

__device__ __forceinline__ float lrelu02(float x) { return x > 0.f ? x : 0.2f * x; }

template <int ALPHA2>
__global__ __launch_bounds__(256) void gat_agg(const ushortT* __restrict__ h,
                                               const float* __restrict__ as_,
                                               const float* __restrict__ ad_,
                                               const int* __restrict__ cnt,
                                               const int* __restrict__ srcs,
                                               const float* __restrict__ bias,
                                               ushortT* __restrict__ out,
                                               const float* __restrict__ w2s,
                                               const float* __restrict__ w2d,
                                               float* __restrict__ as_n,
                                               float* __restrict__ ad_n) {
    int node = blockIdx.x * 8 + (threadIdx.x >> 5);  // 8 nodes per 256-thread block
    int hl = threadIdx.x & 31;                       // lane within half-wave
    if (node >= NN) return;                          // NN % 8 == 0: never taken
    int deg = cnt[node];
    if (deg > BCAP) deg = BCAP;  // impossible for this input class; mem safety
    int rs = node << 6;
    float adst = ad_[node];

    float acc[8] = {0.f, 0.f, 0.f, 0.f, 0.f, 0.f, 0.f, 0.f};

    // pair-uniform max degree (branch must be wave-uniform)
    int maxdeg = max(deg, __shfl_xor(deg, 32));

    if (maxdeg <= 32) {
        int s_lane = srcs[rs + ((hl < deg) ? hl : 0)];

        // ---- issue first 8 row-gathers immediately (independent of softmax) ----
        int s0[8];
#pragma unroll
        for (int t = 0; t < 8; ++t) s0[t] = __shfl(s_lane, (t < deg) ? t : 0, 32);
        bf16x8 hv[8];
#pragma unroll
        for (int t = 0; t < 8; ++t)
            hv[t] = *(const bf16x8*)(h + (size_t)s0[t] * CD + hl * 8);

        // ---- softmax (runs under the gather latency) ----
        float e = (hl < deg) ? lrelu02(as_[s_lane] + adst) : -1e30f;
        float m = e;
#pragma unroll
        for (int off = 1; off < 32; off <<= 1) m = fmaxf(m, __shfl_xor(m, off));
        float ex = (hl < deg) ? __expf(e - m) : 0.f;
        float den = ex;
#pragma unroll
        for (int off = 1; off < 32; off <<= 1) den += __shfl_xor(den, off);
        float wl = ex / den;  // per-lane edge weight (0 for invalid lanes)

        // ---- apply weights to the first batch ----
#pragma unroll
        for (int t = 0; t < 8; ++t) {
            float wv = __shfl(wl, t, 32);
            wv = (t < deg) ? wv : 0.f;
#pragma unroll
            for (int c = 0; c < 8; ++c)
                acc[c] += wv * b2f((ushortT)hv[t][c]);
        }

        // ---- remaining batches (deg > 8; ~45% of pairs, usually 1 extra) ----
        for (int kk = 8; kk < maxdeg; kk += 8) {
            int s[8];
            float w[8];
#pragma unroll
            for (int t = 0; t < 8; ++t) {
                int idx = kk + t;                // wave-uniform
                int ii = (idx < deg) ? idx : 0;  // clamp per half (uniform there)
                int sv = __shfl(s_lane, ii, 32);
                float wv = __shfl(wl, ii, 32);
                s[t] = sv;
                w[t] = (idx < deg) ? wv : 0.f;
            }
            bf16x8 hv2[8];
#pragma unroll
            for (int t = 0; t < 8; ++t)
                hv2[t] = *(const bf16x8*)(h + (size_t)s[t] * CD + hl * 8);
#pragma unroll
            for (int t = 0; t < 8; ++t) {
#pragma unroll
                for (int c = 0; c < 8; ++c)
                    acc[c] += w[t] * b2f((ushortT)hv2[t][c]);
            }
        }
    } else {
        // ---- generic path (pair maxdeg > 32): 32-lane strided loops ----
        int re = rs + deg;
        float m = -1e30f;
        for (int k = rs + hl; k < re; k += 32) {
            float e = lrelu02(as_[srcs[k]] + adst);
            m = fmaxf(m, e);
        }
#pragma unroll
        for (int off = 1; off < 32; off <<= 1) m = fmaxf(m, __shfl_xor(m, off));
        float den = 0.f;
        for (int k = rs + hl; k < re; k += 32) {
            float e = lrelu02(as_[srcs[k]] + adst);
            den += __expf(e - m);
        }
#pragma unroll
        for (int off = 1; off < 32; off <<= 1) den += __shfl_xor(den, off);
        float inv_den = 1.f / den;
        for (int k = rs; k < re; ++k) {
            int sv = srcs[k];
            float e = lrelu02(as_[sv] + adst);
            float wv = __expf(e - m) * inv_den;
            bf16x8 hv = *(const bf16x8*)(h + (size_t)sv * CD + hl * 8);
#pragma unroll
            for (int c = 0; c < 8; ++c)
                acc[c] += wv * b2f((ushortT)hv[c]);
        }
    }

    // ---- epilogue: bias + relu (both convs feed relu), bf16 store ----
    float4 bv0 = *(const float4*)(bias + hl * 8);
    float4 bv1 = *(const float4*)(bias + hl * 8 + 4);
    float r[8];
    r[0] = fmaxf(acc[0] + bv0.x, 0.f);
    r[1] = fmaxf(acc[1] + bv0.y, 0.f);
    r[2] = fmaxf(acc[2] + bv0.z, 0.f);
    r[3] = fmaxf(acc[3] + bv0.w, 0.f);
    r[4] = fmaxf(acc[4] + bv1.x, 0.f);
    r[5] = fmaxf(acc[5] + bv1.y, 0.f);
    r[6] = fmaxf(acc[6] + bv1.z, 0.f);
    r[7] = fmaxf(acc[7] + bv1.w, 0.f);
    bf16x8 o;
#pragma unroll
    for (int c = 0; c < 8; ++c) o[c] = (short)f2b(r[c]);
    *(bf16x8*)(out + (size_t)node * CD + hl * 8) = o;

    if (ALPHA2) {
        float4 s0 = *(const float4*)(w2s + hl * 8);
        float4 s1 = *(const float4*)(w2s + hl * 8 + 4);
        float4 d0 = *(const float4*)(w2d + hl * 8);
        float4 d1 = *(const float4*)(w2d + hl * 8 + 4);
        float ss = r[0] * s0.x + r[1] * s0.y + r[2] * s0.z + r[3] * s0.w +
                   r[4] * s1.x + r[5] * s1.y + r[6] * s1.z + r[7] * s1.w;
        float dd = r[0] * d0.x + r[1] * d0.y + r[2] * d0.z + r[3] * d0.w +
                   r[4] * d1.x + r[5] * d1.y + r[6] * d1.z + r[7] * d1.w;
#pragma unroll
        for (int off = 1; off < 32; off <<= 1) {
            ss += __shfl_xor(ss, off);
            dd += __shfl_xor(dd, off);
        }
        if (hl == 0) {
            as_n[node] = ss;
            ad_n[node] = dd;
        }
    }
}

// ---------------- launch ----------------

extern "C" void kernel_launch(void* const* d_in, const int* in_sizes, int n_in,
                              void* d_out, int out_size, void* d_ws, size_t ws_size,
                              hipStream_t stream) {
    const float* x = (const float*)d_in[0];
    const int* ei = (const int*)d_in[1];
    const float* W1 = (const float*)d_in[2];
    const float* a1s = (const float*)d_in[3];
    const float* a1d = (const float*)d_in[4];
    const float* b1 = (const float*)d_in[5];
    const float* W2 = (const float*)d_in[6];
    const float* a2s = (const float*)d_in[7];
    const float* a2d = (const float*)d_in[8];
    const float* b2 = (const float*)d_in[9];
    const float* Wl = (const float*)d_in[10];
    const float* bl = (const float*)d_in[11];
    float* out = (float*)d_out;

    char* w = (char*)d_ws;
    ushortT* B0 = (ushortT*)w; w += (size_t)PAD_M * CD * 2;
    ushortT* B1 = (ushortT*)w; w += (size_t)PAD_M * CD * 2;
    ushortT* B2 = (ushortT*)w; w += (size_t)PAD_M * CD * 2;
    ushortT* W1t = (ushortT*)w; w += (size_t)CD * CD * 2;
    ushortT* W2t = (ushortT*)w; w += (size_t)CD * CD * 2;
    ushortT* Wlt = (ushortT*)w; w += (size_t)CD * CD * 2;
    float* as1 = (float*)w; w += (size_t)NN * 4;
    float* ad1 = (float*)w; w += (size_t)NN * 4;
    float* as2 = (float*)w; w += (size_t)NN * 4;
    float* ad2 = (float*)w; w += (size_t)NN * 4;
    float* w1s = (float*)w; w += CD * 4;
    float* w1d = (float*)w; w += CD * 4;
    float* w2s = (float*)w; w += CD * 4;
    float* w2d = (float*)w; w += CD * 4;
    int* cnt = (int*)w; w += (size_t)NN * 4;
    int* srcs = (int*)w; w += (size_t)NN * BCAP * 4;  // 12.8 MB buckets

    // alpha-vector precompute + bucket-counter zeroing (first kernel)
    wvec_kernel<<<128, 256, 0, stream>>>(W1, a1s, a1d, W2, a2s, a2d,
                                         w1s, w1d, w2s, w2d, cnt);

    // fused preprocessing: x cast + alpha1 (ILP-4), W transposes, Wl cast,
    // bucket scatter
    prep_kernel<<<PREP_END, 256, 0, stream>>>(x, W1, W2, Wl, B0, W1t, W2t, Wlt,
                                              w1s, w1d, as1, ad1, ei, cnt, srcs);

    int ggrid = (PAD_M / 128) * 4;       // 1568 blocks of 128 rows x 64 cols
    int nagg_blocks = (NN + 7) / 8;      // 6250 blocks, 2 nodes per wave

    // Layer 1
    gemm_mfma<0><<<ggrid, 256, 0, stream>>>(B0, W1t, nullptr, nullptr, B1, NN);
    gat_agg<1><<<nagg_blocks, 256, 0, stream>>>(B1, as1, ad1, cnt, srcs,
                                                b1, B2, w2s, w2d, as2, ad2);

    // Layer 2
    gemm_mfma<0><<<ggrid, 256, 0, stream>>>(B2, W2t, nullptr, nullptr, B1, NN);
    gat_agg<0><<<nagg_blocks, 256, 0, stream>>>(B1, as2, ad2, cnt, srcs,
                                                b2, B0, nullptr, nullptr,
                                                nullptr, nullptr);

    // Final linear: out = B0 @ Wlt^T + bl (fp32 out)
    gemm_mfma<1><<<ggrid, 256, 0, stream>>>(B0, Wlt, bl, out, nullptr, NN);
}

// Round 10
// 260.810 us; speedup vs baseline: 1.1324x; 1.0124x over previous
//
#include <hip/hip_runtime.h>

#define NN 50000
#define EE 300000
#define ET (EE + NN)   // edges + self loops = 350000
#define CD 256
#define PAD_M 50176    // 392 * 128, covers gemm tile over-read
#define BCAP 64        // per-node src bucket capacity (max deg ~25, P(>63)<1e-30)

typedef unsigned short ushortT;
typedef short bf16x8 __attribute__((ext_vector_type(8)));
typedef float f32x4 __attribute__((ext_vector_type(4)));

__device__ __forceinline__ ushortT f2b(float f) {
    unsigned u = __builtin_bit_cast(unsigned, f);
    unsigned r = (u + 0x7FFFu + ((u >> 16) & 1u)) >> 16;
    return (ushortT)r;
}
__device__ __forceinline__ float b2f(ushortT b) {
    return __builtin_bit_cast(float, ((unsigned)b) << 16);
}

// ---------------- alpha-vector precompute: wXs = W @ a_src (row dots) ------
// (x@W)·a == x·(W@a): alpha1 is computed in gemm1's epilogue (from the bf16
// A fragments already in registers) and alpha2 in agg1's epilogue (fp32 acc).
// grid 128: blocks [0,64) -> W1 rows, [64,128) -> W2 rows; wave per row.
// Also zeroes the bucket counters cnt[0..NN) (prep's scatter tail consumes).

__global__ __launch_bounds__(256) void wvec_kernel(
    const float* __restrict__ W1, const float* __restrict__ a1s,
    const float* __restrict__ a1d, const float* __restrict__ W2,
    const float* __restrict__ a2s, const float* __restrict__ a2d,
    float* __restrict__ w1s, float* __restrict__ w1d,
    float* __restrict__ w2s, float* __restrict__ w2d,
    int* __restrict__ cnt) {
    int b = blockIdx.x;
    // bucket-counter zeroing: 128*256 = 32768 threads cover 50000 ints in 2 steps
    int g = b * 256 + threadIdx.x;
    if (g < NN) cnt[g] = 0;
    if (g + 32768 < NN) cnt[g + 32768] = 0;

    const float* W = (b < 64) ? W1 : W2;
    const float* vs = (b < 64) ? a1s : a2s;
    const float* vd = (b < 64) ? a1d : a2d;
    float* os = (b < 64) ? w1s : w2s;
    float* od = (b < 64) ? w1d : w2d;
    int r = (b & 63) * 4 + (threadIdx.x >> 6);
    int lane = threadIdx.x & 63;
    float4 wv = *(const float4*)(W + (size_t)r * CD + lane * 4);
    float4 s4 = *(const float4*)(vs + lane * 4);
    float4 d4 = *(const float4*)(vd + lane * 4);
    float ss = wv.x * s4.x + wv.y * s4.y + wv.z * s4.z + wv.w * s4.w;
    float dd = wv.x * d4.x + wv.y * d4.y + wv.z * d4.z + wv.w * d4.w;
#pragma unroll
    for (int off = 1; off < 64; off <<= 1) {
        ss += __shfl_xor(ss, off);
        dd += __shfl_xor(dd, off);
    }
    if (lane == 0) {
        os[r] = ss;
        od[r] = dd;
    }
}

// ---------------- fused preprocessing ----------------
// x-pass is now a PURE STREAMING CAST (alpha1 moved to gemm1's epilogue —
// round-9 proved the combined load+dot+reduce x-pass stuck at 44 us no
// matter the ILP; a bare cast has no serial tail and should stream).
// [0,3125)      x: cast->bf16, 16 rows/block (4 waves x 4 rows, ILP-4)
// [3125,3189)   transpose-cast W1 -> W1t
// [3189,3253)   transpose-cast W2 -> W2t
// [3253,3317)   straight-cast Wl -> Wlt
// [3317,4685)   bucket scatter (cnt zeroed by wvec; max deg ~25, clamped)
#define PREP_X 3125
#define PREP_W1 3189
#define PREP_W2 3253
#define PREP_WL 3317
#define PREP_END 4685

__global__ __launch_bounds__(256) void prep_kernel(
    const float* __restrict__ x, const float* __restrict__ W1,
    const float* __restrict__ W2, const float* __restrict__ Wl,
    ushortT* __restrict__ B0, ushortT* __restrict__ W1t,
    ushortT* __restrict__ W2t, ushortT* __restrict__ Wlt,
    const int* __restrict__ ei, int* __restrict__ cnt,
    int* __restrict__ srcs) {
    __shared__ float t[32][33];
    int b = blockIdx.x, tidx = threadIdx.x;
    if (b < PREP_X) {
        int row0 = b * 16 + (tidx >> 6) * 4;  // wave's 4 rows
        int lane = tidx & 63;
        const float* xr = x + (size_t)row0 * CD + lane * 4;
        float4 v0 = *(const float4*)(xr);
        float4 v1 = *(const float4*)(xr + CD);
        float4 v2 = *(const float4*)(xr + CD * 2);
        float4 v3 = *(const float4*)(xr + CD * 3);
        ushortT* br = B0 + (size_t)row0 * CD + lane * 4;
        ushort4 o0, o1, o2, o3;
        o0.x = f2b(v0.x); o0.y = f2b(v0.y); o0.z = f2b(v0.z); o0.w = f2b(v0.w);
        o1.x = f2b(v1.x); o1.y = f2b(v1.y); o1.z = f2b(v1.z); o1.w = f2b(v1.w);
        o2.x = f2b(v2.x); o2.y = f2b(v2.y); o2.z = f2b(v2.z); o2.w = f2b(v2.w);
        o3.x = f2b(v3.x); o3.y = f2b(v3.y); o3.z = f2b(v3.z); o3.w = f2b(v3.w);
        *(ushort4*)(br) = o0;
        *(ushort4*)(br + CD) = o1;
        *(ushort4*)(br + CD * 2) = o2;
        *(ushort4*)(br + CD * 3) = o3;
    } else if (b < PREP_W2) {
        const float* W = (b < PREP_W1) ? W1 : W2;
        ushortT* Bt = (b < PREP_W1) ? W1t : W2t;
        int rel = b - ((b < PREP_W1) ? PREP_X : PREP_W1);
        int bx = (rel & 7) * 32;   // k base
        int by = (rel >> 3) * 32;  // n base
        int xx = tidx & 31, yy = tidx >> 5;
        for (int y = yy; y < 32; y += 8) t[y][xx] = W[(size_t)(bx + y) * CD + by + xx];
        __syncthreads();
        for (int y = yy; y < 32; y += 8)
            Bt[(size_t)(by + y) * CD + bx + xx] = f2b(t[xx][y]);
    } else if (b < PREP_WL) {
        int id = (b - PREP_W2) * 256 + tidx;
        float4 v = *(const float4*)(Wl + (size_t)id * 4);
        ushort4 o;
        o.x = f2b(v.x); o.y = f2b(v.y); o.z = f2b(v.z); o.w = f2b(v.w);
        *(ushort4*)(Wlt + (size_t)id * 4) = o;
    } else {
        int i = (b - PREP_WL) * 256 + tidx;
        if (i < EE) {
            int s = ei[i];
            int d = ei[EE + i];
            int p = atomicAdd(&cnt[d], 1);
            if (p < BCAP) srcs[((size_t)d << 6) + p] = s;
        } else if (i < ET) {
            int n = i - EE;
            int p = atomicAdd(&cnt[n], 1);
            if (p < BCAP) srcs[((size_t)n << 6) + p] = n;  // self loop
        }
    }
}

// ---------------- bf16 MFMA GEMM: C[M,256] = A[M,256] @ Bt^T ----------------
// Block = 128 rows x 64 cols, 1-D grid 1568. XCD-aware bijective swizzle
// (1568 = 8*196): id = (bid&7)*196 + (bid>>3) -> the 4 col-siblings (same bm)
// land on ONE per-XCD L2, so A-rows are fetched from HBM once (round-3
// verified; round-8 FETCH counters confirmed the mechanism directly).
// Keep global_load_lds staging + single barrier (round-6 LDS-free REGRESSED;
// round-4 256-row tile REGRESSED; round-8 fp32-A fusion REGRESSED).
// ALPHA1=1 (gemm1 only): bn==0 blocks also emit alpha1 from the bf16 A
// fragments already in registers — as1[r] = row·w1s, ad1[r] = row·w1d,
// reduced over the 4 k-quads with shfl_xor(16,32) (round-2-verified pattern).
// B LDS layout: column-permuted (slot n -> col (n&15)*4+(n>>4)) so lane l15
// owns 4 contiguous output cols -> packed stores; 16B-chunk xor swizzle for
// bank conflicts (measured 0).

template <int OUTF32, int ALPHA1>
__global__ __launch_bounds__(256, 4) void gemm_mfma(const ushortT* __restrict__ A,
                                                    const ushortT* __restrict__ Bt,
                                                    const float* __restrict__ bias,
                                                    float* __restrict__ outF,
                                                    ushortT* __restrict__ outB,
                                                    int M,
                                                    const float* __restrict__ w1s,
                                                    const float* __restrict__ w1d,
                                                    float* __restrict__ as1,
                                                    float* __restrict__ ad1) {
    __shared__ ushortT Bs[64 * 256];  // 32 KB
    int tid = threadIdx.x;
    int wave = tid >> 6, lane = tid & 63;
    int wm = wave * 32;                    // wave's 32-row slice of 128-row block
    int bid = blockIdx.x;
    int id = (bid & 7) * 196 + (bid >> 3);  // XCD-aware bijective swizzle
    int bm = (id >> 2) * 128, bn = (id & 3) * 64;
    int l15 = lane & 15, quad = lane >> 4;

    // ---- B staging: 64 slots x 32 chunks = 2048 16B chunks, 8 rounds ----
#pragma unroll
    for (int p = 0; p < 8; ++p) {
        int c = p * 256 + tid;             // lane-linear flat chunk id
        int slot = c >> 5;                 // LDS slot (permuted col)
        int piece = c & 31;
        int col = (slot & 15) * 4 + (slot >> 4);   // actual col for this slot
        int spiece = piece ^ (slot & 31);  // physical chunk p holds data chunk p^slot
        const ushortT* gb = Bt + (size_t)(bn + col) * CD + spiece * 8;
        __builtin_amdgcn_global_load_lds(
            (const __attribute__((address_space(1))) void*)gb,
            (__attribute__((address_space(3))) void*)(Bs + (size_t)(p * 256 + wave * 64) * 8),
            16, 0, 0);
    }

    // ---- hoist ALL A fragments (16 independent 16B loads in flight) ----
    bf16x8 a[2][8];
#pragma unroll
    for (int kk = 0; kk < 8; ++kk)
#pragma unroll
        for (int i = 0; i < 2; ++i)
            a[i][kk] = *(const bf16x8*)(A + (size_t)(bm + wm + i * 16 + l15) * CD + kk * 32 + quad * 8);

    __syncthreads();

    f32x4 acc[2][4] = {};

    // ---- K loop: pure LDS + MFMA ----
#pragma unroll
    for (int kk = 0; kk < 8; ++kk) {
        bf16x8 b[4];
        int kc = kk * 4 + quad;  // data chunk index within slot
#pragma unroll
        for (int j = 0; j < 4; ++j) {
            int slot = j * 16 + l15;
            b[j] = *(const bf16x8*)(Bs + (size_t)slot * 256 + (size_t)(kc ^ (slot & 31)) * 8);
        }
#pragma unroll
        for (int i = 0; i < 2; ++i)
#pragma unroll
            for (int j = 0; j < 4; ++j)
                acc[i][j] = __builtin_amdgcn_mfma_f32_16x16x32_bf16(a[i][kk], b[j], acc[i][j], 0, 0, 0);
    }

    // ---- epilogue: lane l15 owns 4 contiguous cols bn+4*l15.. across j ----
    int colb = bn + l15 * 4;
#pragma unroll
    for (int i = 0; i < 2; ++i) {
#pragma unroll
        for (int r = 0; r < 4; ++r) {
            int row = bm + wm + i * 16 + quad * 4 + r;
            if (OUTF32) {
                if (row < M) {
                    float4 bv = *(const float4*)(bias + colb);
                    float4 v;
                    v.x = acc[i][0][r] + bv.x;
                    v.y = acc[i][1][r] + bv.y;
                    v.z = acc[i][2][r] + bv.z;
                    v.w = acc[i][3][r] + bv.w;
                    *(float4*)(outF + (size_t)row * CD + colb) = v;
                }
            } else {
                ushort4 o;
                o.x = f2b(acc[i][0][r]);
                o.y = f2b(acc[i][1][r]);
                o.z = f2b(acc[i][2][r]);
                o.w = f2b(acc[i][3][r]);
                *(ushort4*)(outB + (size_t)row * CD + colb) = o;  // ws padded
            }
        }
    }

    // ---- ALPHA1: alpha from the bf16 A fragments (bn==0 blocks only) ----
    if (ALPHA1) {
        if (bn == 0) {
            float ss0 = 0.f, sd0 = 0.f, ss1 = 0.f, sd1 = 0.f;
#pragma unroll
            for (int kk = 0; kk < 8; ++kk) {
                int cb = kk * 32 + quad * 8;
                float4 ws0 = *(const float4*)(w1s + cb);
                float4 ws1 = *(const float4*)(w1s + cb + 4);
                float4 wd0 = *(const float4*)(w1d + cb);
                float4 wd1 = *(const float4*)(w1d + cb + 4);
                float x0[8], x1[8];
#pragma unroll
                for (int e = 0; e < 8; ++e) {
                    x0[e] = b2f((ushortT)a[0][kk][e]);
                    x1[e] = b2f((ushortT)a[1][kk][e]);
                }
                ss0 += x0[0] * ws0.x + x0[1] * ws0.y + x0[2] * ws0.z + x0[3] * ws0.w +
                       x0[4] * ws1.x + x0[5] * ws1.y + x0[6] * ws1.z + x0[7] * ws1.w;
                sd0 += x0[0] * wd0.x + x0[1] * wd0.y + x0[2] * wd0.z + x0[3] * wd0.w +
                       x0[4] * wd1.x + x0[5] * wd1.y + x0[6] * wd1.z + x0[7] * wd1.w;
                ss1 += x1[0] * ws0.x + x1[1] * ws0.y + x1[2] * ws0.z + x1[3] * ws0.w +
                       x1[4] * ws1.x + x1[5] * ws1.y + x1[6] * ws1.z + x1[7] * ws1.w;
                sd1 += x1[0] * wd0.x + x1[1] * wd0.y + x1[2] * wd0.z + x1[3] * wd0.w +
                       x1[4] * wd1.x + x1[5] * wd1.y + x1[6] * wd1.z + x1[7] * wd1.w;
            }
#pragma unroll
            for (int off = 16; off < 64; off <<= 1) {
                ss0 += __shfl_xor(ss0, off);
                sd0 += __shfl_xor(sd0, off);
                ss1 += __shfl_xor(ss1, off);
                sd1 += __shfl_xor(sd1, off);
            }
            if (lane < 16) {
                int r0 = bm + wm + l15;
                int r1 = r0 + 16;
                if (r0 < NN) { as1[r0] = ss0; ad1[r0] = sd0; }
                if (r1 < NN) { as1[r1] = ss1; ad1[r1] = sd1; }
            }
        }
    }
}

// ---------------- GAT aggregation: TWO dst nodes per wave (32 lanes each) --
// Half-wave per node, lane owns 8 contiguous cols (16B loads/stores).
// Bucketed adjacency: rs = node<<6, deg = cnt[node].
// Latency-hiding order: issue the first 8 h-row gathers (addresses depend
// only on s_lane) BEFORE the softmax's as_-gather + shfl chain.
// ALPHA2=1: also emit next layer's alpha from the fp32 pre-cast row.

__device__ __forceinline__ float lrelu02(float x) { return x > 0.f ? x : 0.2f * x; }

template <int ALPHA2>
__global__ __launch_bounds__(256) void gat_agg(const ushortT* __restrict__ h,
                                               const float* __restrict__ as_,
                                               const float* __restrict__ ad_,
                                               const int* __restrict__ cnt,
                                               const int* __restrict__ srcs,
                                               const float* __restrict__ bias,
                                               ushortT* __restrict__ out,
                                               const float* __restrict__ w2s,
                                               const float* __restrict__ w2d,
                                               float* __restrict__ as_n,
                                               float* __restrict__ ad_n) {
    int node = blockIdx.x * 8 + (threadIdx.x >> 5);  // 8 nodes per 256-thread block
    int hl = threadIdx.x & 31;                       // lane within half-wave
    if (node >= NN) return;                          // NN % 8 == 0: never taken
    int deg = cnt[node];
    if (deg > BCAP) deg = BCAP;  // impossible for this input class; mem safety
    int rs = node << 6;
    float adst = ad_[node];

    float acc[8] = {0.f, 0.f, 0.f, 0.f, 0.f, 0.f, 0.f, 0.f};

    // pair-uniform max degree (branch must be wave-uniform)
    int maxdeg = max(deg, __shfl_xor(deg, 32));

    if (maxdeg <= 32) {
        int s_lane = srcs[rs + ((hl < deg) ? hl : 0)];

        // ---- issue first 8 row-gathers immediately (independent of softmax) ----
        int s0[8];
#pragma unroll
        for (int t = 0; t < 8; ++t) s0[t] = __shfl(s_lane, (t < deg) ? t : 0, 32);
        bf16x8 hv[8];
#pragma unroll
        for (int t = 0; t < 8; ++t)
            hv[t] = *(const bf16x8*)(h + (size_t)s0[t] * CD + hl * 8);

        // ---- softmax (runs under the gather latency) ----
        float e = (hl < deg) ? lrelu02(as_[s_lane] + adst) : -1e30f;
        float m = e;
#pragma unroll
        for (int off = 1; off < 32; off <<= 1) m = fmaxf(m, __shfl_xor(m, off));
        float ex = (hl < deg) ? __expf(e - m) : 0.f;
        float den = ex;
#pragma unroll
        for (int off = 1; off < 32; off <<= 1) den += __shfl_xor(den, off);
        float wl = ex / den;  // per-lane edge weight (0 for invalid lanes)

        // ---- apply weights to the first batch ----
#pragma unroll
        for (int t = 0; t < 8; ++t) {
            float wv = __shfl(wl, t, 32);
            wv = (t < deg) ? wv : 0.f;
#pragma unroll
            for (int c = 0; c < 8; ++c)
                acc[c] += wv * b2f((ushortT)hv[t][c]);
        }

        // ---- remaining batches (deg > 8; ~45% of pairs, usually 1 extra) ----
        for (int kk = 8; kk < maxdeg; kk += 8) {
            int s[8];
            float w[8];
#pragma unroll
            for (int t = 0; t < 8; ++t) {
                int idx = kk + t;                // wave-uniform
                int ii = (idx < deg) ? idx : 0;  // clamp per half (uniform there)
                int sv = __shfl(s_lane, ii, 32);
                float wv = __shfl(wl, ii, 32);
                s[t] = sv;
                w[t] = (idx < deg) ? wv : 0.f;
            }
            bf16x8 hv2[8];
#pragma unroll
            for (int t = 0; t < 8; ++t)
                hv2[t] = *(const bf16x8*)(h + (size_t)s[t] * CD + hl * 8);
#pragma unroll
            for (int t = 0; t < 8; ++t) {
#pragma unroll
                for (int c = 0; c < 8; ++c)
                    acc[c] += w[t] * b2f((ushortT)hv2[t][c]);
            }
        }
    } else {
        // ---- generic path (pair maxdeg > 32): 32-lane strided loops ----
        int re = rs + deg;
        float m = -1e30f;
        for (int k = rs + hl; k < re; k += 32) {
            float e = lrelu02(as_[srcs[k]] + adst);
            m = fmaxf(m, e);
        }
#pragma unroll
        for (int off = 1; off < 32; off <<= 1) m = fmaxf(m, __shfl_xor(m, off));
        float den = 0.f;
        for (int k = rs + hl; k < re; k += 32) {
            float e = lrelu02(as_[srcs[k]] + adst);
            den += __expf(e - m);
        }
#pragma unroll
        for (int off = 1; off < 32; off <<= 1) den += __shfl_xor(den, off);
        float inv_den = 1.f / den;
        for (int k = rs; k < re; ++k) {
            int sv = srcs[k];
            float e = lrelu02(as_[sv] + adst);
            float wv = __expf(e - m) * inv_den;
            bf16x8 hv = *(const bf16x8*)(h + (size_t)sv * CD + hl * 8);
#pragma unroll
            for (int c = 0; c < 8; ++c)
                acc[c] += wv * b2f((ushortT)hv[c]);
        }
    }

    // ---- epilogue: bias + relu (both convs feed relu), bf16 store ----
    float4 bv0 = *(const float4*)(bias + hl * 8);
    float4 bv1 = *(const float4*)(bias + hl * 8 + 4);
    float r[8];
    r[0] = fmaxf(acc[0] + bv0.x, 0.f);
    r[1] = fmaxf(acc[1] + bv0.y, 0.f);
    r[2] = fmaxf(acc[2] + bv0.z, 0.f);
    r[3] = fmaxf(acc[3] + bv0.w, 0.f);
    r[4] = fmaxf(acc[4] + bv1.x, 0.f);
    r[5] = fmaxf(acc[5] + bv1.y, 0.f);
    r[6] = fmaxf(acc[6] + bv1.z, 0.f);
    r[7] = fmaxf(acc[7] + bv1.w, 0.f);
    bf16x8 o;
#pragma unroll
    for (int c = 0; c < 8; ++c) o[c] = (short)f2b(r[c]);
    *(bf16x8*)(out + (size_t)node * CD + hl * 8) = o;

    if (ALPHA2) {
        float4 s0 = *(const float4*)(w2s + hl * 8);
        float4 s1 = *(const float4*)(w2s + hl * 8 + 4);
        float4 d0 = *(const float4*)(w2d + hl * 8);
        float4 d1 = *(const float4*)(w2d + hl * 8 + 4);
        float ss = r[0] * s0.x + r[1] * s0.y + r[2] * s0.z + r[3] * s0.w +
                   r[4] * s1.x + r[5] * s1.y + r[6] * s1.z + r[7] * s1.w;
        float dd = r[0] * d0.x + r[1] * d0.y + r[2] * d0.z + r[3] * d0.w +
                   r[4] * d1.x + r[5] * d1.y + r[6] * d1.z + r[7] * d1.w;
#pragma unroll
        for (int off = 1; off < 32; off <<= 1) {
            ss += __shfl_xor(ss, off);
            dd += __shfl_xor(dd, off);
        }
        if (hl == 0) {
            as_n[node] = ss;
            ad_n[node] = dd;
        }
    }
}

// ---------------- launch ----------------

extern "C" void kernel_launch(void* const* d_in, const int* in_sizes, int n_in,
                              void* d_out, int out_size, void* d_ws, size_t ws_size,
                              hipStream_t stream) {
    const float* x = (const float*)d_in[0];
    const int* ei = (const int*)d_in[1];
    const float* W1 = (const float*)d_in[2];
    const float* a1s = (const float*)d_in[3];
    const float* a1d = (const float*)d_in[4];
    const float* b1 = (const float*)d_in[5];
    const float* W2 = (const float*)d_in[6];
    const float* a2s = (const float*)d_in[7];
    const float* a2d = (const float*)d_in[8];
    const float* b2 = (const float*)d_in[9];
    const float* Wl = (const float*)d_in[10];
    const float* bl = (const float*)d_in[11];
    float* out = (float*)d_out;

    char* w = (char*)d_ws;
    ushortT* B0 = (ushortT*)w; w += (size_t)PAD_M * CD * 2;
    ushortT* B1 = (ushortT*)w; w += (size_t)PAD_M * CD * 2;
    ushortT* B2 = (ushortT*)w; w += (size_t)PAD_M * CD * 2;
    ushortT* W1t = (ushortT*)w; w += (size_t)CD * CD * 2;
    ushortT* W2t = (ushortT*)w; w += (size_t)CD * CD * 2;
    ushortT* Wlt = (ushortT*)w; w += (size_t)CD * CD * 2;
    float* as1 = (float*)w; w += (size_t)NN * 4;
    float* ad1 = (float*)w; w += (size_t)NN * 4;
    float* as2 = (float*)w; w += (size_t)NN * 4;
    float* ad2 = (float*)w; w += (size_t)NN * 4;
    float* w1s = (float*)w; w += CD * 4;
    float* w1d = (float*)w; w += CD * 4;
    float* w2s = (float*)w; w += CD * 4;
    float* w2d = (float*)w; w += CD * 4;
    int* cnt = (int*)w; w += (size_t)NN * 4;
    int* srcs = (int*)w; w += (size_t)NN * BCAP * 4;  // 12.8 MB buckets

    // alpha-vector precompute + bucket-counter zeroing (first kernel)
    wvec_kernel<<<128, 256, 0, stream>>>(W1, a1s, a1d, W2, a2s, a2d,
                                         w1s, w1d, w2s, w2d, cnt);

    // fused preprocessing: pure x cast, W transposes, Wl cast, bucket scatter
    prep_kernel<<<PREP_END, 256, 0, stream>>>(x, W1, W2, Wl, B0, W1t, W2t, Wlt,
                                              ei, cnt, srcs);

    int ggrid = (PAD_M / 128) * 4;       // 1568 blocks of 128 rows x 64 cols
    int nagg_blocks = (NN + 7) / 8;      // 6250 blocks, 2 nodes per wave

    // Layer 1 (gemm1 also emits alpha1 from its A fragments)
    gemm_mfma<0, 1><<<ggrid, 256, 0, stream>>>(B0, W1t, nullptr, nullptr, B1, NN,
                                               w1s, w1d, as1, ad1);
    gat_agg<1><<<nagg_blocks, 256, 0, stream>>>(B1, as1, ad1, cnt, srcs,
                                                b1, B2, w2s, w2d, as2, ad2);

    // Layer 2
    gemm_mfma<0, 0><<<ggrid, 256, 0, stream>>>(B2, W2t, nullptr, nullptr, B1, NN,
                                               nullptr, nullptr, nullptr, nullptr);
    gat_agg<0><<<nagg_blocks, 256, 0, stream>>>(B1, as2, ad2, cnt, srcs,
                                                b2, B0, nullptr, nullptr,
                                                nullptr, nullptr);

    // Final linear: out = B0 @ Wlt^T + bl (fp32 out)
    gemm_mfma<1, 0><<<ggrid, 256, 0, stream>>>(B0, Wlt, bl, out, nullptr, NN,
                                               nullptr, nullptr, nullptr, nullptr);
}